// Round 17
// baseline (413.901 us; speedup 1.0000x reference)
//
#include <hip/hip_runtime.h>
#include <hip/hip_bf16.h>

typedef unsigned short ushort_t;
typedef unsigned int uint_t;
typedef _Float16 h2v __attribute__((ext_vector_type(2)));
typedef uint_t uvec32 __attribute__((ext_vector_type(32)));

#define N_NOTES 2000
#define N_CHUNKS 128
#define WARMUP 80

__device__ __forceinline__ float sigm(float x) { return 1.0f / (1.0f + __expf(-x)); }
__device__ __forceinline__ float tanhc(float x) {
    x = fminf(fmaxf(x, -15.f), 15.f);
    float e = __expf(2.f * x);
    return (e - 1.f) / (e + 1.f);
}
__device__ __forceinline__ uint_t pk2(float a, float b) {
    h2v h; h[0] = (_Float16)a; h[1] = (_Float16)b;
    return __builtin_bit_cast(uint_t, h);
}

#if __has_builtin(__builtin_amdgcn_fdot2)
__device__ __forceinline__ float fdot2f(uint_t a, uint_t b, float c) {
    return __builtin_amdgcn_fdot2(__builtin_bit_cast(h2v, a), __builtin_bit_cast(h2v, b), c, false);
}
#else
__device__ __forceinline__ float fdot2f(uint_t a, uint_t b, float c) {
    h2v x = __builtin_bit_cast(h2v, a), y = __builtin_bit_cast(h2v, b);
    return c + (float)x[0] * (float)y[0] + (float)x[1] * (float)y[1];
}
#endif

// ---- DPP cross-lane (VALU pipe) ----
template <int CTRL, int RMASK = 0xF>
__device__ __forceinline__ float dppmov(float src, float old) {
    int r = __builtin_amdgcn_update_dpp(__builtin_bit_cast(int, old),
                                        __builtin_bit_cast(int, src),
                                        CTRL, RMASK, 0xF, false);
    return __builtin_bit_cast(float, r);
}
template <int CTRL>
__device__ __forceinline__ float qp(float v) { return dppmov<CTRL>(v, v); }
__device__ __forceinline__ float rdl(float v, int l) {
    return __builtin_bit_cast(float, __builtin_amdgcn_readlane(__builtin_bit_cast(int, v), l));
}
#define WRED_ADD(x) do { x += qp<0xB1>(x); x += qp<0x4E>(x); x += qp<0x141>(x); x += qp<0x140>(x); \
                         x += __shfl_xor(x, 16); x += __shfl_xor(x, 32); } while (0)
#define WRED_MAX(x) do { x = fmaxf(x, qp<0xB1>(x)); x = fmaxf(x, qp<0x4E>(x)); \
                         x = fmaxf(x, qp<0x141>(x)); x = fmaxf(x, qp<0x140>(x)); \
                         x = fmaxf(x, __shfl_xor(x, 16)); x = fmaxf(x, __shfl_xor(x, 32)); } while (0)

#define BAR() do { \
    asm volatile("s_waitcnt lgkmcnt(0)" ::: "memory"); \
    __builtin_amdgcn_s_barrier(); \
    asm volatile("" ::: "memory"); \
} while (0)
#define LGKM0() asm volatile("s_waitcnt lgkmcnt(0)" ::: "memory")

// ---------------- fused pre: opre + tpre (pz inline; be/me staged once) ----------------
__global__ __launch_bounds__(512, 2) void pre_kernel(
    const float* __restrict__ oWih, const float* __restrict__ obih, const float* __restrict__ obhh,
    const float* __restrict__ tWih, const float* __restrict__ tbih, const float* __restrict__ tbhh,
    const float* __restrict__ ne, const float* __restrict__ be, const float* __restrict__ me,
    const float* __restrict__ ri, const float* __restrict__ expW, const float* __restrict__ expb,
    const float* __restrict__ perf, const float* __restrict__ fcb,
    const int* __restrict__ bn, const int* __restrict__ mn,
    float* __restrict__ opre, float* __restrict__ tpre) {
    const int i0 = blockIdx.x * 16;
    const int j = threadIdx.x;
    const int R = ((j & 3) << 7) + (j >> 2);   // gate-major row
    __shared__ float xs[16][256];
    __shared__ float xm[16][128];
    __shared__ float xr[16][8];
    __shared__ float pz_l[64];
    __shared__ float fcb_l[10];
    if (j < 64) {
        float acc = expb[j];
#pragma unroll
        for (int k = 0; k < 16; k++) acc += expW[j * 16 + k] * perf[k];
        pz_l[j] = fmaxf(acc, 0.f);
    }
    if (j < 10) fcb_l[j] = fcb[j];
    const int bn0 = bn[0], mn0 = mn[0];
    __syncthreads();
    const float* wo = oWih + R * 715;
    const float* wt = tWih + R * 467;
    float tail_o = obih[R] + obhh[R];
#pragma unroll
    for (int r = 0; r < 10; r++) tail_o += wo[641 + r] * fcb_l[r];
#pragma unroll 8
    for (int k = 0; k < 64; k++) tail_o += wo[651 + k] * pz_l[k];
    float tail_t = tbih[R] + tbhh[R];
#pragma unroll 8
    for (int k = 0; k < 64; k++) tail_t += wt[403 + k] * pz_l[k];
    float acco[16], acct[16];
#pragma unroll
    for (int m = 0; m < 16; m++) { acco[m] = tail_o; acct[m] = tail_t; }
    // phase 1: ne -> o cols 0..255
    for (int t = j; t < 16 * 256; t += 512) xs[t >> 8][t & 255] = ne[i0 * 256 + t];
    __syncthreads();
#pragma unroll 4
    for (int k = 0; k < 256; k++) {
        float wv = wo[k];
#pragma unroll
        for (int m = 0; m < 16; m++) acco[m] += wv * xs[m][k];
    }
    __syncthreads();
    // phase 2: be -> o cols 256..511 AND t cols 0..255; ri -> t cols 385..392
    for (int t = j; t < 16 * 256; t += 512) {
        int m = t >> 8, k = t & 255;
        xs[m][k] = be[(bn[i0 + m] - bn0) * 256 + k];
    }
    if (j < 128) {
        int m = j >> 3, k = j & 7;
        xr[m][k] = ri[(bn[i0 + m] - bn0) * 8 + k];
    }
    __syncthreads();
#pragma unroll 2
    for (int k = 0; k < 256; k++) {
        float wv1 = wo[256 + k];
        float wv2 = wt[k];
#pragma unroll
        for (int m = 0; m < 16; m++) {
            float x = xs[m][k];
            acco[m] += wv1 * x;
            acct[m] += wv2 * x;
        }
    }
#pragma unroll
    for (int k = 0; k < 8; k++) {
        float wv = wt[385 + k];
#pragma unroll
        for (int m = 0; m < 16; m++) acct[m] += wv * xr[m][k];
    }
    __syncthreads();
    // phase 3: me -> o cols 512..639 AND t cols 256..383
    for (int t = j; t < 16 * 128; t += 512) {
        int m = t >> 7, k = t & 127;
        xm[m][k] = me[(mn[i0 + m] - mn0) * 128 + k];
    }
    __syncthreads();
#pragma unroll 2
    for (int k = 0; k < 128; k++) {
        float wv1 = wo[512 + k];
        float wv2 = wt[256 + k];
#pragma unroll
        for (int m = 0; m < 16; m++) {
            float x = xm[m][k];
            acco[m] += wv1 * x;
            acct[m] += wv2 * x;
        }
    }
#pragma unroll
    for (int m = 0; m < 16; m++) {
        opre[(i0 + m) * 512 + j] = acco[m];
        tpre[(i0 + m) * 512 + j] = acct[m];
    }
}

// fc+sim -> rings, optionally out[NOTE,1:11].
#define FC_SIM_RING(FHP_OFF, NOTE, OUTOK) do { \
    const int r_ = lane & 15; \
    const int cch_ = lane >> 4; \
    const uint4* fv_ = (const uint4*)(fh_pk + (FHP_OFF)) + (cch_ << 2); \
    const uint4* wv_ = (const uint4*)(fcw_pk + r_ * 68) + (cch_ << 2); \
    float a0_ = 0.f, a1_ = 0.f, a2_ = 0.f, a3_ = 0.f; \
    _Pragma("unroll") \
    for (int q_ = 0; q_ < 4; q_++) { \
        uint4 aa_ = wv_[q_]; uint4 bb_ = fv_[q_]; \
        a0_ = fdot2f(aa_.x, bb_.x, a0_); \
        a1_ = fdot2f(aa_.y, bb_.y, a1_); \
        a2_ = fdot2f(aa_.z, bb_.z, a2_); \
        a3_ = fdot2f(aa_.w, bb_.w, a3_); \
    } \
    float acc_ = (a0_ + a1_) + (a2_ + a3_); \
    acc_ += __shfl_xor(acc_, 16); \
    acc_ += __shfl_xor(acc_, 32); \
    float ofc_ = acc_ + fcb_lds[r_]; \
    float a_ = attnb_lds[r_]; \
    _Pragma("unroll") \
    for (int c_ = 0; c_ < 10; c_++) a_ += attnW_lds[r_ * 10 + c_] * rdl(ofc_, c_); \
    float simv_ = tanhc(a_) * attncv_lds[r_]; \
    simv_ += qp<0xB1>(simv_); \
    simv_ += qp<0x4E>(simv_); \
    simv_ += qp<0x141>(simv_); \
    simv_ += qp<0x140>(simv_); \
    if (lane < 10) { \
        out_ring[((NOTE) & 255) * 10 + lane] = ofc_; \
        if (OUTOK) out[(NOTE) * 11 + 1 + lane] = ofc_; \
    } \
    if (lane == 0) sim_ring[(NOTE) & 255] = simv_; \
} while (0)

// ---------------- chunked scan: N_CHUNKS blocks, self-computed bounds, direct out writes ----------------
__global__
__attribute__((amdgpu_flat_work_group_size(512, 512), amdgpu_waves_per_eu(2, 2)))
void seq_kernel(
    const float* __restrict__ oWih, const float* __restrict__ oWhh,
    const float* __restrict__ tWih, const float* __restrict__ tWhh,
    const float* __restrict__ fcW, const float* __restrict__ fcb,
    const float* __restrict__ tfcW, const float* __restrict__ tfcb,
    const float* __restrict__ attnW, const float* __restrict__ attnb,
    const float* __restrict__ attncv,
    const int* __restrict__ bn_g,
    const float* __restrict__ opre, const float* __restrict__ tpre,
    float* __restrict__ out) {
    const int j = threadIdx.x;
    const int lane = j & 63;
    const int wv_id = j >> 6;
    const int blk = blockIdx.x;

    __shared__ __align__(16) uint_t t2_lds[512 * 64];
    __shared__ __align__(16) uint_t fh_pk[2 * 64];
    __shared__ __align__(16) uint_t th_pk[2 * 64];
    __shared__ __align__(16) uint_t fcw_pk[16 * 68];
    __shared__ float attnW_lds[160];
    __shared__ float attnb_lds[16], attncv_lds[16], fcb_lds[16];
    __shared__ uint_t rn_pk[5];
    __shared__ float rn_tmp[10];
    __shared__ __align__(16) float tpart8[8];
    __shared__ float out_ring[256 * 10];
    __shared__ float sim_ring[256];
    __shared__ unsigned char bnd_lds[2048];

    for (int idx = j; idx < 16 * 68; idx += 512) {
        int r = idx / 68, k = idx - r * 68;
        uint_t v = 0;
        if (r < 10 && k < 64) v = pk2(fcW[r * 128 + 2 * k], fcW[r * 128 + 2 * k + 1]);
        fcw_pk[idx] = v;
    }
    for (int idx = j; idx < N_NOTES; idx += 512)
        bnd_lds[idx] = (idx == 0) ? 1 : (bn_g[idx] > bn_g[idx - 1]);
    if (j < 160) attnW_lds[j] = (j < 100) ? attnW[j] : 0.f;
    if (j < 16) {
        attnb_lds[j] = (j < 10) ? attnb[j] : 0.f;
        attncv_lds[j] = (j < 10) ? attncv[j] : 0.f;
        fcb_lds[j] = (j < 10) ? fcb[j] : 0.f;
    }
    if (j < 5) rn_pk[j] = 0;
    if (j < 128) { fh_pk[j] = 0; th_pk[j] = 0; }
    if (j < 8) tpart8[j] = 0.f;
    __syncthreads();

    // ---- chunk bounds (all threads compute identically from bnd_lds) ----
    int s = (blk * N_NOTES) / N_CHUNKS;
    while (s > 0 && !bnd_lds[s]) s--;
    const int ostart = s;
    int w = ostart - WARMUP;
    if (w < 0) w = 0;
    while (w > 0 && !bnd_lds[w]) w--;
    const int wstart = w;
    int e = N_NOTES;
    if (blk + 1 < N_CHUNKS) {
        e = ((blk + 1) * N_NOTES) / N_CHUNKS;
        while (e > 0 && !bnd_lds[e]) e--;
    }
    const int iend = e;

    const int R = ((j & 3) << 7) + (j >> 2);
    const int u = j >> 2;
    const int g = j & 3;
    float c1[10];
#pragma unroll
    for (int r = 0; r < 10; r++) c1[r] = oWih[R * 715 + 641 + r];
    float d0 = 0.f;
#pragma unroll
    for (int r = 0; r < 10; r++) d0 += c1[r] * fcb_lds[r];
    const float ocol = oWih[R * 715 + 640];
    const float twc384 = tWih[R * 467 + 384];
    uvec32 w2a, w2b;
    {
        const float* owr = oWhh + R * 128;
#pragma unroll
        for (int q = 0; q < 32; q++) {
            float a = owr[2 * q], b = owr[2 * q + 1];
#pragma unroll
            for (int r = 0; r < 10; r++) {
                a += c1[r] * fcW[r * 128 + 2 * q];
                b += c1[r] * fcW[r * 128 + 2 * q + 1];
            }
            w2a[q] = pk2(a, b);
        }
#pragma unroll
        for (int q = 0; q < 32; q++) {
            float a = owr[64 + 2 * q], b = owr[64 + 2 * q + 1];
#pragma unroll
            for (int r = 0; r < 10; r++) {
                a += c1[r] * fcW[r * 128 + 64 + 2 * q];
                b += c1[r] * fcW[r * 128 + 64 + 2 * q + 1];
            }
            w2b[q] = pk2(a, b);
        }
    }
    {
        const float* twr = tWhh + R * 128;
#pragma unroll
        for (int q = 0; q < 64; q++) {
            uint_t v = pk2(twr[2 * q] + twc384 * tfcW[2 * q],
                           twr[2 * q + 1] + twc384 * tfcW[2 * q + 1]);
            t2_lds[j * 64 + (((q >> 2) ^ (j & 15)) << 2) + (q & 3)] = v;
        }
    }
    uint_t twcp[5];
#pragma unroll
    for (int r = 0; r < 5; r++)
        twcp[r] = pk2(tWih[R * 467 + 393 + 2 * r], tWih[R * 467 + 393 + 2 * r + 1]);
    const float const_t = twc384 * tfcb[0];
    const float tfcw_u = tfcW[u];
    const float tfcb_s = tfcb[0];

    float c_st = 0.f, tc_st = 0.f;
    float tempo_reg = 0.f;
    int prev_end = wstart;
    int bp = 0;
    bool bnd_prev = false;
    bool bnd_cur = true;   // wstart is a boundary by construction
    float pre_o = opre[wstart * 512 + j];
    float pre_t = tpre[wstart * 512 + j];
    __syncthreads();

#pragma unroll 1
    for (int i = wstart; i < iend; ++i) {
        if (bnd_prev) {
            float4 p0 = *(const float4*)&tpart8[0];
            float4 p1 = *(const float4*)&tpart8[4];
            tempo_reg = ((p0.x + p0.y) + (p0.z + p0.w)) + ((p1.x + p1.y) + (p1.z + p1.w)) + tfcb_s;
        }
        if (j == 0 && i > wstart && (i - 1) >= ostart) out[(i - 1) * 11] = tempo_reg;
        const int par = i & 1;
        const int ip1 = (i + 1 < iend) ? (i + 1) : (iend - 1);
        // global boundary flag: also fires at i == iend-1 (iend is next chunk's ostart)
        const bool bnd_nxt = (i + 1 < N_NOTES) && bnd_lds[i + 1];
        const float pre_o_nxt = opre[ip1 * 512 + j];
        const float pre_t_nxt = tpre[ip1 * 512 + j];
        {
            float zb = pre_o + ocol * tempo_reg;
            if (i == 0) zb -= d0;
            const uint4* fp = (const uint4*)(fh_pk + ((par ^ 1) << 6));
            float a0 = zb, a1 = 0.f, a2 = 0.f, a3 = 0.f;
#pragma unroll
            for (int q = 0; q < 8; q++) {
                uint4 v = fp[q];
                a0 = fdot2f(w2a[4 * q + 0], v.x, a0);
                a1 = fdot2f(w2a[4 * q + 1], v.y, a1);
                a2 = fdot2f(w2a[4 * q + 2], v.z, a2);
                a3 = fdot2f(w2a[4 * q + 3], v.w, a3);
            }
#pragma unroll
            for (int q = 0; q < 8; q++) {
                uint4 v = fp[8 + q];
                a0 = fdot2f(w2b[4 * q + 0], v.x, a0);
                a1 = fdot2f(w2b[4 * q + 1], v.y, a1);
                a2 = fdot2f(w2b[4 * q + 2], v.z, a2);
                a3 = fdot2f(w2b[4 * q + 3], v.w, a3);
            }
            float z = (a0 + a1) + (a2 + a3);
            float x1 = qp<0xB1>(z);
            float x2 = qp<0x4E>(z);
            float x3 = qp<0x1B>(z);
            float zi = (g == 1) ? x1 : (g == 2) ? x2 : (g == 3) ? x3 : z;
            float zf = (g == 0) ? x1 : (g == 1) ? z  : (g == 2) ? x3 : x2;
            float zg = (g == 0) ? x2 : (g == 1) ? x3 : (g == 2) ? z  : x1;
            float zo = (g == 0) ? x3 : (g == 1) ? x2 : (g == 2) ? x1 : z;
            c_st = sigm(zf) * c_st + sigm(zi) * tanhc(zg);
            float h = sigm(zo) * tanhc(c_st);
            if (g == 0) ((_Float16*)fh_pk)[(par << 7) + u] = (_Float16)h;
        }
        if (bnd_cur) {
            float ztb = (i == 0) ? 0.f : const_t;
#pragma unroll
            for (int r = 0; r < 5; r++) ztb = fdot2f(twcp[r], rn_pk[r], ztb);
            const uint4* t2v = (const uint4*)t2_lds + (j << 4);
            const uint4* thv = (const uint4*)(th_pk + ((bp ^ 1) << 6));
            float b0 = pre_t + ztb, b1 = 0.f, b2 = 0.f, b3 = 0.f;
#pragma unroll
            for (int s2 = 0; s2 < 16; s2++) {
                uint4 w2 = t2v[s2 ^ (j & 15)];
                uint4 v = thv[s2];
                b0 = fdot2f(w2.x, v.x, b0);
                b1 = fdot2f(w2.y, v.y, b1);
                b2 = fdot2f(w2.z, v.z, b2);
                b3 = fdot2f(w2.w, v.w, b3);
            }
            float zt = (b0 + b1) + (b2 + b3);
            float y1 = qp<0xB1>(zt);
            float y2 = qp<0x4E>(zt);
            float y3 = qp<0x1B>(zt);
            float ti = (g == 1) ? y1 : (g == 2) ? y2 : (g == 3) ? y3 : zt;
            float tf = (g == 0) ? y1 : (g == 1) ? zt : (g == 2) ? y3 : y2;
            float tg = (g == 0) ? y2 : (g == 1) ? y3 : (g == 2) ? zt : y1;
            float to = (g == 0) ? y3 : (g == 1) ? y2 : (g == 2) ? y1 : zt;
            tc_st = sigm(tf) * tc_st + sigm(ti) * tanhc(tg);
            float th = sigm(to) * tanhc(tc_st);
            if (g == 0) ((_Float16*)th_pk)[(bp << 7) + u] = (_Float16)th;
            float qv = 0.25f * tfcw_u * th;
            qv += qp<0xB1>(qv);
            qv += qp<0x4E>(qv);
            qv += qp<0x141>(qv);
            qv += qp<0x140>(qv);
            qv += dppmov<0x142, 0xA>(qv, 0.f);
            qv += dppmov<0x143, 0xC>(qv, 0.f);
            float wsum = rdl(qv, 63);
            if (lane == 0) tpart8[wv_id] = wsum;
            prev_end = i;
        } else if (i > wstart && wv_id == (i & 7)) {
            // deferred fc/sim/out for note i-1
            FC_SIM_RING(((par ^ 1) << 6), i - 1, (i - 1) >= ostart);
        }
        BAR();
        if (bnd_nxt) {
            if (j < 64) {
                // eager fc/sim/out for note i (the pre-boundary note)
                FC_SIM_RING((par << 6), i, i >= ostart);
                LGKM0();
                const int L = i + 1 - prev_end;
                float m = -1e30f;
                for (int b = lane; b < L; b += 64) m = fmaxf(m, sim_ring[(prev_end + b) & 255]);
                WRED_MAX(m);
                float es = 0.f;
                float accv[10];
#pragma unroll
                for (int r = 0; r < 10; r++) accv[r] = 0.f;
                for (int b = lane; b < L; b += 64) {
                    int idx = (prev_end + b) & 255;
                    float e2 = __expf(sim_ring[idx] - m);
                    es += e2;
#pragma unroll
                    for (int r = 0; r < 10; r++) accv[r] += e2 * out_ring[idx * 10 + r];
                }
                WRED_ADD(es);
#pragma unroll
                for (int r = 0; r < 10; r++) WRED_ADD(accv[r]);
                float inv = 1.f / fmaxf(es, 1e-20f);
                if (lane < 10) rn_tmp[lane] = accv[lane] * inv;
                LGKM0();
                if (lane < 5) rn_pk[lane] = pk2(rn_tmp[2 * lane], rn_tmp[2 * lane + 1]);
            }
            BAR();
        }
        bnd_prev = bnd_cur;
        if (bnd_cur) bp ^= 1;
        pre_o = pre_o_nxt;
        pre_t = pre_t_nxt;
        bnd_cur = bnd_nxt;
    }
    // final tempo of this chunk's range
    if (bnd_prev) {
        float4 p0 = *(const float4*)&tpart8[0];
        float4 p1 = *(const float4*)&tpart8[4];
        tempo_reg = ((p0.x + p0.y) + (p0.z + p0.w)) + ((p1.x + p1.y) + (p1.z + p1.w)) + tfcb_s;
    }
    if (j == 0 && iend > wstart && (iend - 1) >= ostart) out[(iend - 1) * 11] = tempo_reg;
    // epilogue fc for the global last note (no eager covers it; last chunk only)
    if (iend == N_NOTES && iend > wstart && j < 64) {
        FC_SIM_RING((((N_NOTES - 1) & 1) << 6), N_NOTES - 1, true);
    }
}

extern "C" void kernel_launch(void* const* d_in, const int* in_sizes, int n_in,
                              void* d_out, int out_size, void* d_ws, size_t ws_size,
                              hipStream_t stream) {
    (void)in_sizes; (void)n_in; (void)out_size; (void)ws_size;
    const float* ne     = (const float*)d_in[0];
    const float* be     = (const float*)d_in[1];
    const float* me     = (const float*)d_in[2];
    const float* ri     = (const float*)d_in[3];
    const float* perf   = (const float*)d_in[4];
    const int*   bn     = (const int*)d_in[5];
    const int*   mn     = (const int*)d_in[6];
    const float* expW   = (const float*)d_in[7];
    const float* expb   = (const float*)d_in[8];
    const float* tWih   = (const float*)d_in[9];
    const float* tWhh   = (const float*)d_in[10];
    const float* tbih   = (const float*)d_in[11];
    const float* tbhh   = (const float*)d_in[12];
    const float* tfcW   = (const float*)d_in[13];
    const float* tfcb   = (const float*)d_in[14];
    const float* attnW  = (const float*)d_in[15];
    const float* attnb  = (const float*)d_in[16];
    const float* attncv = (const float*)d_in[17];
    const float* oWih   = (const float*)d_in[18];
    const float* oWhh   = (const float*)d_in[19];
    const float* obih   = (const float*)d_in[20];
    const float* obhh   = (const float*)d_in[21];
    const float* fcW    = (const float*)d_in[22];
    const float* fcb    = (const float*)d_in[23];

    float* opre = (float*)d_ws;
    float* tpre = opre + N_NOTES * 512;
    float* out  = (float*)d_out;

    pre_kernel<<<N_NOTES / 16, 512, 0, stream>>>(oWih, obih, obhh, tWih, tbih, tbhh,
                                                 ne, be, me, ri, expW, expb, perf, fcb,
                                                 bn, mn, opre, tpre);
    seq_kernel<<<N_CHUNKS, 512, 0, stream>>>(oWih, oWhh, tWih, tWhh, fcW, fcb, tfcW, tfcb,
                                             attnW, attnb, attncv, bn, opre, tpre, out);
}

// Round 19
// 303.176 us; speedup vs baseline: 1.3652x; 1.3652x over previous
//
#include <hip/hip_runtime.h>
#include <hip/hip_bf16.h>

typedef unsigned short ushort_t;
typedef unsigned int uint_t;
typedef _Float16 h2v __attribute__((ext_vector_type(2)));
typedef uint_t uvec32 __attribute__((ext_vector_type(32)));

#define N_NOTES 2000
#define N_CHUNKS 128
#define WARMUP 80
#define NB 125   // N_NOTES/16

__device__ __forceinline__ float sigm(float x) { return 1.0f / (1.0f + __expf(-x)); }
__device__ __forceinline__ float tanhc(float x) {
    x = fminf(fmaxf(x, -15.f), 15.f);
    float e = __expf(2.f * x);
    return (e - 1.f) / (e + 1.f);
}
__device__ __forceinline__ uint_t pk2(float a, float b) {
    h2v h; h[0] = (_Float16)a; h[1] = (_Float16)b;
    return __builtin_bit_cast(uint_t, h);
}

#if __has_builtin(__builtin_amdgcn_fdot2)
__device__ __forceinline__ float fdot2f(uint_t a, uint_t b, float c) {
    return __builtin_amdgcn_fdot2(__builtin_bit_cast(h2v, a), __builtin_bit_cast(h2v, b), c, false);
}
#else
__device__ __forceinline__ float fdot2f(uint_t a, uint_t b, float c) {
    h2v x = __builtin_bit_cast(h2v, a), y = __builtin_bit_cast(h2v, b);
    return c + (float)x[0] * (float)y[0] + (float)x[1] * (float)y[1];
}
#endif

// ---- DPP cross-lane (VALU pipe) ----
template <int CTRL, int RMASK = 0xF>
__device__ __forceinline__ float dppmov(float src, float old) {
    int r = __builtin_amdgcn_update_dpp(__builtin_bit_cast(int, old),
                                        __builtin_bit_cast(int, src),
                                        CTRL, RMASK, 0xF, false);
    return __builtin_bit_cast(float, r);
}
template <int CTRL>
__device__ __forceinline__ float qp(float v) { return dppmov<CTRL>(v, v); }
__device__ __forceinline__ float rdl(float v, int l) {
    return __builtin_bit_cast(float, __builtin_amdgcn_readlane(__builtin_bit_cast(int, v), l));
}
#define WRED_ADD(x) do { x += qp<0xB1>(x); x += qp<0x4E>(x); x += qp<0x141>(x); x += qp<0x140>(x); \
                         x += __shfl_xor(x, 16); x += __shfl_xor(x, 32); } while (0)
#define WRED_MAX(x) do { x = fmaxf(x, qp<0xB1>(x)); x = fmaxf(x, qp<0x4E>(x)); \
                         x = fmaxf(x, qp<0x141>(x)); x = fmaxf(x, qp<0x140>(x)); \
                         x = fmaxf(x, __shfl_xor(x, 16)); x = fmaxf(x, __shfl_xor(x, 32)); } while (0)

#define BAR() do { \
    asm volatile("s_waitcnt lgkmcnt(0)" ::: "memory"); \
    __builtin_amdgcn_s_barrier(); \
    asm volatile("" ::: "memory"); \
} while (0)
#define LGKM0() asm volatile("s_waitcnt lgkmcnt(0)" ::: "memory")

// ---------------- pre: concatenated grids — blocks 0..124 opre, 125..249 tpre ----------------
__global__ __launch_bounds__(512, 2) void pre_kernel(
    const float* __restrict__ oWih, const float* __restrict__ obih, const float* __restrict__ obhh,
    const float* __restrict__ tWih, const float* __restrict__ tbih, const float* __restrict__ tbhh,
    const float* __restrict__ ne, const float* __restrict__ be, const float* __restrict__ me,
    const float* __restrict__ ri, const float* __restrict__ expW, const float* __restrict__ expb,
    const float* __restrict__ perf, const float* __restrict__ fcb,
    const int* __restrict__ bn, const int* __restrict__ mn,
    float* __restrict__ opre, float* __restrict__ tpre) {
    const int j = threadIdx.x;
    const int R = ((j & 3) << 7) + (j >> 2);   // gate-major row
    __shared__ float xs[16][256];
    __shared__ float xm[16][128];
    __shared__ float xr[16][8];
    __shared__ float pz_l[64];
    __shared__ float fcb_l[10];
    if (j < 64) {
        float acc = expb[j];
#pragma unroll
        for (int k = 0; k < 16; k++) acc += expW[j * 16 + k] * perf[k];
        pz_l[j] = fmaxf(acc, 0.f);
    }
    if (j < 10) fcb_l[j] = fcb[j];
    const int bn0 = bn[0], mn0 = mn[0];

    if (blockIdx.x < NB) {
        // ================= opre role =================
        const int i0 = blockIdx.x * 16;
        __syncthreads();
        const float* w = oWih + R * 715;
        float tail = obih[R] + obhh[R];
#pragma unroll
        for (int r = 0; r < 10; r++) tail += w[641 + r] * fcb_l[r];
#pragma unroll 8
        for (int k = 0; k < 64; k++) tail += w[651 + k] * pz_l[k];
        float acc[16];
#pragma unroll
        for (int m = 0; m < 16; m++) acc[m] = tail;
        for (int t = j; t < 16 * 256; t += 512) xs[t >> 8][t & 255] = ne[i0 * 256 + t];
        __syncthreads();
#pragma unroll 4
        for (int k = 0; k < 256; k++) {
            float wv = w[k];
#pragma unroll
            for (int m = 0; m < 16; m++) acc[m] += wv * xs[m][k];
        }
        __syncthreads();
        for (int t = j; t < 16 * 256; t += 512) {
            int m = t >> 8, k = t & 255;
            xs[m][k] = be[(bn[i0 + m] - bn0) * 256 + k];
        }
        __syncthreads();
#pragma unroll 4
        for (int k = 0; k < 256; k++) {
            float wv = w[256 + k];
#pragma unroll
            for (int m = 0; m < 16; m++) acc[m] += wv * xs[m][k];
        }
        __syncthreads();
        for (int t = j; t < 16 * 128; t += 512) {
            int m = t >> 7, k = t & 127;
            xm[m][k] = me[(mn[i0 + m] - mn0) * 128 + k];
        }
        __syncthreads();
#pragma unroll 4
        for (int k = 0; k < 128; k++) {
            float wv = w[512 + k];
#pragma unroll
            for (int m = 0; m < 16; m++) acc[m] += wv * xm[m][k];
        }
#pragma unroll
        for (int m = 0; m < 16; m++) opre[(i0 + m) * 512 + j] = acc[m];
    } else {
        // ================= tpre role =================
        const int i0 = (blockIdx.x - NB) * 16;
        {
            bool need = false;
#pragma unroll
            for (int m = 0; m < 16; m++) {
                int idx = i0 + m;
                need = need || (idx == 0) || (bn[idx] > bn[idx - 1]);
            }
            if (!need) return;
        }
        __syncthreads();
        const float* w = tWih + R * 467;
        float tail = tbih[R] + tbhh[R];
#pragma unroll 8
        for (int k = 0; k < 64; k++) tail += w[403 + k] * pz_l[k];
        float acc[16];
#pragma unroll
        for (int m = 0; m < 16; m++) acc[m] = tail;
        for (int t = j; t < 16 * 256; t += 512) {
            int m = t >> 8, k = t & 255;
            xs[m][k] = be[(bn[i0 + m] - bn0) * 256 + k];
        }
        if (j < 128) {
            int m = j >> 3, k = j & 7;
            xr[m][k] = ri[(bn[i0 + m] - bn0) * 8 + k];
        }
        __syncthreads();
#pragma unroll 4
        for (int k = 0; k < 256; k++) {
            float wv = w[k];
#pragma unroll
            for (int m = 0; m < 16; m++) acc[m] += wv * xs[m][k];
        }
#pragma unroll
        for (int k = 0; k < 8; k++) {
            float wv = w[385 + k];
#pragma unroll
            for (int m = 0; m < 16; m++) acc[m] += wv * xr[m][k];
        }
        __syncthreads();
        for (int t = j; t < 16 * 128; t += 512) {
            int m = t >> 7, k = t & 127;
            xm[m][k] = me[(mn[i0 + m] - mn0) * 128 + k];
        }
        __syncthreads();
#pragma unroll 4
        for (int k = 0; k < 128; k++) {
            float wv = w[256 + k];
#pragma unroll
            for (int m = 0; m < 16; m++) acc[m] += wv * xm[m][k];
        }
#pragma unroll
        for (int m = 0; m < 16; m++) tpre[(i0 + m) * 512 + j] = acc[m];
    }
}

// fc+sim -> rings, optionally out[NOTE,1:11].
#define FC_SIM_RING(FHP_OFF, NOTE, OUTOK) do { \
    const int r_ = lane & 15; \
    const int cch_ = lane >> 4; \
    const uint4* fv_ = (const uint4*)(fh_pk + (FHP_OFF)) + (cch_ << 2); \
    const uint4* wv_ = (const uint4*)(fcw_pk + r_ * 68) + (cch_ << 2); \
    float a0_ = 0.f, a1_ = 0.f, a2_ = 0.f, a3_ = 0.f; \
    _Pragma("unroll") \
    for (int q_ = 0; q_ < 4; q_++) { \
        uint4 aa_ = wv_[q_]; uint4 bb_ = fv_[q_]; \
        a0_ = fdot2f(aa_.x, bb_.x, a0_); \
        a1_ = fdot2f(aa_.y, bb_.y, a1_); \
        a2_ = fdot2f(aa_.z, bb_.z, a2_); \
        a3_ = fdot2f(aa_.w, bb_.w, a3_); \
    } \
    float acc_ = (a0_ + a1_) + (a2_ + a3_); \
    acc_ += __shfl_xor(acc_, 16); \
    acc_ += __shfl_xor(acc_, 32); \
    float ofc_ = acc_ + fcb_lds[r_]; \
    float a_ = attnb_lds[r_]; \
    _Pragma("unroll") \
    for (int c_ = 0; c_ < 10; c_++) a_ += attnW_lds[r_ * 10 + c_] * rdl(ofc_, c_); \
    float simv_ = tanhc(a_) * attncv_lds[r_]; \
    simv_ += qp<0xB1>(simv_); \
    simv_ += qp<0x4E>(simv_); \
    simv_ += qp<0x141>(simv_); \
    simv_ += qp<0x140>(simv_); \
    if (lane < 10) { \
        out_ring[((NOTE) & 255) * 10 + lane] = ofc_; \
        if (OUTOK) out[(NOTE) * 11 + 1 + lane] = ofc_; \
    } \
    if (lane == 0) sim_ring[(NOTE) & 255] = simv_; \
} while (0)

// ---------------- chunked scan: N_CHUNKS blocks, self-computed bounds, direct out writes ----------------
__global__
__attribute__((amdgpu_flat_work_group_size(512, 512), amdgpu_waves_per_eu(2, 2)))
void seq_kernel(
    const float* __restrict__ oWih, const float* __restrict__ oWhh,
    const float* __restrict__ tWih, const float* __restrict__ tWhh,
    const float* __restrict__ fcW, const float* __restrict__ fcb,
    const float* __restrict__ tfcW, const float* __restrict__ tfcb,
    const float* __restrict__ attnW, const float* __restrict__ attnb,
    const float* __restrict__ attncv,
    const int* __restrict__ bn_g,
    const float* __restrict__ opre, const float* __restrict__ tpre,
    float* __restrict__ out) {
    const int j = threadIdx.x;
    const int lane = j & 63;
    const int wv_id = j >> 6;
    const int blk = blockIdx.x;

    __shared__ __align__(16) uint_t t2_lds[512 * 64];
    __shared__ __align__(16) uint_t fh_pk[2 * 64];
    __shared__ __align__(16) uint_t th_pk[2 * 64];
    __shared__ __align__(16) uint_t fcw_pk[16 * 68];
    __shared__ float attnW_lds[160];
    __shared__ float attnb_lds[16], attncv_lds[16], fcb_lds[16];
    __shared__ uint_t rn_pk[5];
    __shared__ float rn_tmp[10];
    __shared__ __align__(16) float tpart8[8];
    __shared__ float out_ring[256 * 10];
    __shared__ float sim_ring[256];
    __shared__ unsigned char bnd_lds[2048];

    for (int idx = j; idx < 16 * 68; idx += 512) {
        int r = idx / 68, k = idx - r * 68;
        uint_t v = 0;
        if (r < 10 && k < 64) v = pk2(fcW[r * 128 + 2 * k], fcW[r * 128 + 2 * k + 1]);
        fcw_pk[idx] = v;
    }
    for (int idx = j; idx < N_NOTES; idx += 512)
        bnd_lds[idx] = (idx == 0) ? 1 : (bn_g[idx] > bn_g[idx - 1]);
    if (j < 160) attnW_lds[j] = (j < 100) ? attnW[j] : 0.f;
    if (j < 16) {
        attnb_lds[j] = (j < 10) ? attnb[j] : 0.f;
        attncv_lds[j] = (j < 10) ? attncv[j] : 0.f;
        fcb_lds[j] = (j < 10) ? fcb[j] : 0.f;
    }
    if (j < 5) rn_pk[j] = 0;
    if (j < 128) { fh_pk[j] = 0; th_pk[j] = 0; }
    if (j < 8) tpart8[j] = 0.f;
    __syncthreads();

    // ---- chunk bounds (all threads compute identically from bnd_lds) ----
    int s = (blk * N_NOTES) / N_CHUNKS;
    while (s > 0 && !bnd_lds[s]) s--;
    const int ostart = s;
    int w = ostart - WARMUP;
    if (w < 0) w = 0;
    while (w > 0 && !bnd_lds[w]) w--;
    const int wstart = w;
    int e = N_NOTES;
    if (blk + 1 < N_CHUNKS) {
        e = ((blk + 1) * N_NOTES) / N_CHUNKS;
        while (e > 0 && !bnd_lds[e]) e--;
    }
    const int iend = e;

    const int R = ((j & 3) << 7) + (j >> 2);
    const int u = j >> 2;
    const int g = j & 3;
    float c1[10];
#pragma unroll
    for (int r = 0; r < 10; r++) c1[r] = oWih[R * 715 + 641 + r];
    float d0 = 0.f;
#pragma unroll
    for (int r = 0; r < 10; r++) d0 += c1[r] * fcb_lds[r];
    const float ocol = oWih[R * 715 + 640];
    const float twc384 = tWih[R * 467 + 384];
    uvec32 w2a, w2b;
    {
        const float* owr = oWhh + R * 128;
#pragma unroll
        for (int q = 0; q < 32; q++) {
            float a = owr[2 * q], b = owr[2 * q + 1];
#pragma unroll
            for (int r = 0; r < 10; r++) {
                a += c1[r] * fcW[r * 128 + 2 * q];
                b += c1[r] * fcW[r * 128 + 2 * q + 1];
            }
            w2a[q] = pk2(a, b);
        }
#pragma unroll
        for (int q = 0; q < 32; q++) {
            float a = owr[64 + 2 * q], b = owr[64 + 2 * q + 1];
#pragma unroll
            for (int r = 0; r < 10; r++) {
                a += c1[r] * fcW[r * 128 + 64 + 2 * q];
                b += c1[r] * fcW[r * 128 + 64 + 2 * q + 1];
            }
            w2b[q] = pk2(a, b);
        }
    }
    {
        const float* twr = tWhh + R * 128;
#pragma unroll
        for (int q = 0; q < 64; q++) {
            uint_t v = pk2(twr[2 * q] + twc384 * tfcW[2 * q],
                           twr[2 * q + 1] + twc384 * tfcW[2 * q + 1]);
            t2_lds[j * 64 + (((q >> 2) ^ (j & 15)) << 2) + (q & 3)] = v;
        }
    }
    uint_t twcp[5];
#pragma unroll
    for (int r = 0; r < 5; r++)
        twcp[r] = pk2(tWih[R * 467 + 393 + 2 * r], tWih[R * 467 + 393 + 2 * r + 1]);
    const float const_t = twc384 * tfcb[0];
    const float tfcw_u = tfcW[u];
    const float tfcb_s = tfcb[0];

    float c_st = 0.f, tc_st = 0.f;
    float tempo_reg = 0.f;
    int prev_end = wstart;
    int bp = 0;
    bool bnd_prev = false;
    bool bnd_cur = true;   // wstart is a boundary by construction
    float pre_o = opre[wstart * 512 + j];
    float pre_t = tpre[wstart * 512 + j];
    __syncthreads();

#pragma unroll 1
    for (int i = wstart; i < iend; ++i) {
        if (bnd_prev) {
            float4 p0 = *(const float4*)&tpart8[0];
            float4 p1 = *(const float4*)&tpart8[4];
            tempo_reg = ((p0.x + p0.y) + (p0.z + p0.w)) + ((p1.x + p1.y) + (p1.z + p1.w)) + tfcb_s;
        }
        if (j == 0 && i > wstart && (i - 1) >= ostart) out[(i - 1) * 11] = tempo_reg;
        const int par = i & 1;
        const int ip1 = (i + 1 < iend) ? (i + 1) : (iend - 1);
        // global boundary flag: also fires at i == iend-1 (iend is next chunk's ostart)
        const bool bnd_nxt = (i + 1 < N_NOTES) && bnd_lds[i + 1];
        const float pre_o_nxt = opre[ip1 * 512 + j];
        const float pre_t_nxt = tpre[ip1 * 512 + j];
        {
            float zb = pre_o + ocol * tempo_reg;
            if (i == 0) zb -= d0;
            const uint4* fp = (const uint4*)(fh_pk + ((par ^ 1) << 6));
            float a0 = zb, a1 = 0.f, a2 = 0.f, a3 = 0.f;
#pragma unroll
            for (int q = 0; q < 8; q++) {
                uint4 v = fp[q];
                a0 = fdot2f(w2a[4 * q + 0], v.x, a0);
                a1 = fdot2f(w2a[4 * q + 1], v.y, a1);
                a2 = fdot2f(w2a[4 * q + 2], v.z, a2);
                a3 = fdot2f(w2a[4 * q + 3], v.w, a3);
            }
#pragma unroll
            for (int q = 0; q < 8; q++) {
                uint4 v = fp[8 + q];
                a0 = fdot2f(w2b[4 * q + 0], v.x, a0);
                a1 = fdot2f(w2b[4 * q + 1], v.y, a1);
                a2 = fdot2f(w2b[4 * q + 2], v.z, a2);
                a3 = fdot2f(w2b[4 * q + 3], v.w, a3);
            }
            float z = (a0 + a1) + (a2 + a3);
            float x1 = qp<0xB1>(z);
            float x2 = qp<0x4E>(z);
            float x3 = qp<0x1B>(z);
            float zi = (g == 1) ? x1 : (g == 2) ? x2 : (g == 3) ? x3 : z;
            float zf = (g == 0) ? x1 : (g == 1) ? z  : (g == 2) ? x3 : x2;
            float zg = (g == 0) ? x2 : (g == 1) ? x3 : (g == 2) ? z  : x1;
            float zo = (g == 0) ? x3 : (g == 1) ? x2 : (g == 2) ? x1 : z;
            c_st = sigm(zf) * c_st + sigm(zi) * tanhc(zg);
            float h = sigm(zo) * tanhc(c_st);
            if (g == 0) ((_Float16*)fh_pk)[(par << 7) + u] = (_Float16)h;
        }
        if (bnd_cur) {
            float ztb = (i == 0) ? 0.f : const_t;
#pragma unroll
            for (int r = 0; r < 5; r++) ztb = fdot2f(twcp[r], rn_pk[r], ztb);
            const uint4* t2v = (const uint4*)t2_lds + (j << 4);
            const uint4* thv = (const uint4*)(th_pk + ((bp ^ 1) << 6));
            float b0 = pre_t + ztb, b1 = 0.f, b2 = 0.f, b3 = 0.f;
#pragma unroll
            for (int s2 = 0; s2 < 16; s2++) {
                uint4 w2 = t2v[s2 ^ (j & 15)];
                uint4 v = thv[s2];
                b0 = fdot2f(w2.x, v.x, b0);
                b1 = fdot2f(w2.y, v.y, b1);
                b2 = fdot2f(w2.z, v.z, b2);
                b3 = fdot2f(w2.w, v.w, b3);
            }
            float zt = (b0 + b1) + (b2 + b3);
            float y1 = qp<0xB1>(zt);
            float y2 = qp<0x4E>(zt);
            float y3 = qp<0x1B>(zt);
            float ti = (g == 1) ? y1 : (g == 2) ? y2 : (g == 3) ? y3 : zt;
            float tf = (g == 0) ? y1 : (g == 1) ? zt : (g == 2) ? y3 : y2;
            float tg = (g == 0) ? y2 : (g == 1) ? y3 : (g == 2) ? zt : y1;
            float to = (g == 0) ? y3 : (g == 1) ? y2 : (g == 2) ? y1 : zt;
            tc_st = sigm(tf) * tc_st + sigm(ti) * tanhc(tg);
            float th = sigm(to) * tanhc(tc_st);
            if (g == 0) ((_Float16*)th_pk)[(bp << 7) + u] = (_Float16)th;
            float qv = 0.25f * tfcw_u * th;
            qv += qp<0xB1>(qv);
            qv += qp<0x4E>(qv);
            qv += qp<0x141>(qv);
            qv += qp<0x140>(qv);
            qv += dppmov<0x142, 0xA>(qv, 0.f);
            qv += dppmov<0x143, 0xC>(qv, 0.f);
            float wsum = rdl(qv, 63);
            if (lane == 0) tpart8[wv_id] = wsum;
            prev_end = i;
        } else if (i > wstart && wv_id == (i & 7)) {
            // deferred fc/sim/out for note i-1
            FC_SIM_RING(((par ^ 1) << 6), i - 1, (i - 1) >= ostart);
        }
        BAR();
        if (bnd_nxt) {
            if (j < 64) {
                // eager fc/sim/out for note i (the pre-boundary note)
                FC_SIM_RING((par << 6), i, i >= ostart);
                LGKM0();
                const int L = i + 1 - prev_end;
                float m = -1e30f;
                for (int b = lane; b < L; b += 64) m = fmaxf(m, sim_ring[(prev_end + b) & 255]);
                WRED_MAX(m);
                float es = 0.f;
                float accv[10];
#pragma unroll
                for (int r = 0; r < 10; r++) accv[r] = 0.f;
                for (int b = lane; b < L; b += 64) {
                    int idx = (prev_end + b) & 255;
                    float e2 = __expf(sim_ring[idx] - m);
                    es += e2;
#pragma unroll
                    for (int r = 0; r < 10; r++) accv[r] += e2 * out_ring[idx * 10 + r];
                }
                WRED_ADD(es);
#pragma unroll
                for (int r = 0; r < 10; r++) WRED_ADD(accv[r]);
                float inv = 1.f / fmaxf(es, 1e-20f);
                if (lane < 10) rn_tmp[lane] = accv[lane] * inv;
                LGKM0();
                if (lane < 5) rn_pk[lane] = pk2(rn_tmp[2 * lane], rn_tmp[2 * lane + 1]);
            }
            BAR();
        }
        bnd_prev = bnd_cur;
        if (bnd_cur) bp ^= 1;
        pre_o = pre_o_nxt;
        pre_t = pre_t_nxt;
        bnd_cur = bnd_nxt;
    }
    // final tempo of this chunk's range
    if (bnd_prev) {
        float4 p0 = *(const float4*)&tpart8[0];
        float4 p1 = *(const float4*)&tpart8[4];
        tempo_reg = ((p0.x + p0.y) + (p0.z + p0.w)) + ((p1.x + p1.y) + (p1.z + p1.w)) + tfcb_s;
    }
    if (j == 0 && iend > wstart && (iend - 1) >= ostart) out[(iend - 1) * 11] = tempo_reg;
    // epilogue fc for the global last note (no eager covers it; last chunk only)
    if (iend == N_NOTES && iend > wstart && j < 64) {
        FC_SIM_RING((((N_NOTES - 1) & 1) << 6), N_NOTES - 1, true);
    }
}

extern "C" void kernel_launch(void* const* d_in, const int* in_sizes, int n_in,
                              void* d_out, int out_size, void* d_ws, size_t ws_size,
                              hipStream_t stream) {
    (void)in_sizes; (void)n_in; (void)out_size; (void)ws_size;
    const float* ne     = (const float*)d_in[0];
    const float* be     = (const float*)d_in[1];
    const float* me     = (const float*)d_in[2];
    const float* ri     = (const float*)d_in[3];
    const float* perf   = (const float*)d_in[4];
    const int*   bn     = (const int*)d_in[5];
    const int*   mn     = (const int*)d_in[6];
    const float* expW   = (const float*)d_in[7];
    const float* expb   = (const float*)d_in[8];
    const float* tWih   = (const float*)d_in[9];
    const float* tWhh   = (const float*)d_in[10];
    const float* tbih   = (const float*)d_in[11];
    const float* tbhh   = (const float*)d_in[12];
    const float* tfcW   = (const float*)d_in[13];
    const float* tfcb   = (const float*)d_in[14];
    const float* attnW  = (const float*)d_in[15];
    const float* attnb  = (const float*)d_in[16];
    const float* attncv = (const float*)d_in[17];
    const float* oWih   = (const float*)d_in[18];
    const float* oWhh   = (const float*)d_in[19];
    const float* obih   = (const float*)d_in[20];
    const float* obhh   = (const float*)d_in[21];
    const float* fcW    = (const float*)d_in[22];
    const float* fcb    = (const float*)d_in[23];

    float* opre = (float*)d_ws;
    float* tpre = opre + N_NOTES * 512;
    float* out  = (float*)d_out;

    pre_kernel<<<2 * NB, 512, 0, stream>>>(oWih, obih, obhh, tWih, tbih, tbhh,
                                           ne, be, me, ri, expW, expb, perf, fcb,
                                           bn, mn, opre, tpre);
    seq_kernel<<<N_CHUNKS, 512, 0, stream>>>(oWih, oWhh, tWih, tWhh, fcW, fcb, tfcW, tfcb,
                                             attnW, attnb, attncv, bn, opre, tpre, out);
}

// Round 20
// 282.528 us; speedup vs baseline: 1.4650x; 1.0731x over previous
//
#include <hip/hip_runtime.h>
#include <hip/hip_bf16.h>

typedef unsigned short ushort_t;
typedef unsigned int uint_t;
typedef _Float16 h2v __attribute__((ext_vector_type(2)));
typedef uint_t uvec32 __attribute__((ext_vector_type(32)));

#define N_NOTES 2000
#define N_CHUNKS 256
#define WARMUP 72
#define NB 125   // N_NOTES/16

__device__ __forceinline__ float sigm(float x) { return 1.0f / (1.0f + __expf(-x)); }
__device__ __forceinline__ float tanhc(float x) {
    x = fminf(fmaxf(x, -15.f), 15.f);
    float e = __expf(2.f * x);
    return (e - 1.f) / (e + 1.f);
}
__device__ __forceinline__ uint_t pk2(float a, float b) {
    h2v h; h[0] = (_Float16)a; h[1] = (_Float16)b;
    return __builtin_bit_cast(uint_t, h);
}

#if __has_builtin(__builtin_amdgcn_fdot2)
__device__ __forceinline__ float fdot2f(uint_t a, uint_t b, float c) {
    return __builtin_amdgcn_fdot2(__builtin_bit_cast(h2v, a), __builtin_bit_cast(h2v, b), c, false);
}
#else
__device__ __forceinline__ float fdot2f(uint_t a, uint_t b, float c) {
    h2v x = __builtin_bit_cast(h2v, a), y = __builtin_bit_cast(h2v, b);
    return c + (float)x[0] * (float)y[0] + (float)x[1] * (float)y[1];
}
#endif

// ---- DPP cross-lane (VALU pipe) ----
template <int CTRL, int RMASK = 0xF>
__device__ __forceinline__ float dppmov(float src, float old) {
    int r = __builtin_amdgcn_update_dpp(__builtin_bit_cast(int, old),
                                        __builtin_bit_cast(int, src),
                                        CTRL, RMASK, 0xF, false);
    return __builtin_bit_cast(float, r);
}
template <int CTRL>
__device__ __forceinline__ float qp(float v) { return dppmov<CTRL>(v, v); }
__device__ __forceinline__ float rdl(float v, int l) {
    return __builtin_bit_cast(float, __builtin_amdgcn_readlane(__builtin_bit_cast(int, v), l));
}
#define WRED_ADD(x) do { x += qp<0xB1>(x); x += qp<0x4E>(x); x += qp<0x141>(x); x += qp<0x140>(x); \
                         x += __shfl_xor(x, 16); x += __shfl_xor(x, 32); } while (0)
#define WRED_MAX(x) do { x = fmaxf(x, qp<0xB1>(x)); x = fmaxf(x, qp<0x4E>(x)); \
                         x = fmaxf(x, qp<0x141>(x)); x = fmaxf(x, qp<0x140>(x)); \
                         x = fmaxf(x, __shfl_xor(x, 16)); x = fmaxf(x, __shfl_xor(x, 32)); } while (0)

#define BAR() do { \
    asm volatile("s_waitcnt lgkmcnt(0)" ::: "memory"); \
    __builtin_amdgcn_s_barrier(); \
    asm volatile("" ::: "memory"); \
} while (0)
#define LGKM0() asm volatile("s_waitcnt lgkmcnt(0)" ::: "memory")

// ---------------- pre: concatenated grids — blocks 0..124 opre, 125..249 tpre ----------------
__global__ __launch_bounds__(512, 2) void pre_kernel(
    const float* __restrict__ oWih, const float* __restrict__ obih, const float* __restrict__ obhh,
    const float* __restrict__ tWih, const float* __restrict__ tbih, const float* __restrict__ tbhh,
    const float* __restrict__ ne, const float* __restrict__ be, const float* __restrict__ me,
    const float* __restrict__ ri, const float* __restrict__ expW, const float* __restrict__ expb,
    const float* __restrict__ perf, const float* __restrict__ fcb,
    const int* __restrict__ bn, const int* __restrict__ mn,
    float* __restrict__ opre, float* __restrict__ tpre) {
    const int j = threadIdx.x;
    const int R = ((j & 3) << 7) + (j >> 2);   // gate-major row
    __shared__ float xs[16][256];
    __shared__ float xm[16][128];
    __shared__ float xr[16][8];
    __shared__ float pz_l[64];
    __shared__ float fcb_l[10];
    if (j < 64) {
        float acc = expb[j];
#pragma unroll
        for (int k = 0; k < 16; k++) acc += expW[j * 16 + k] * perf[k];
        pz_l[j] = fmaxf(acc, 0.f);
    }
    if (j < 10) fcb_l[j] = fcb[j];
    const int bn0 = bn[0], mn0 = mn[0];

    if (blockIdx.x < NB) {
        // ================= opre role =================
        const int i0 = blockIdx.x * 16;
        __syncthreads();
        const float* w = oWih + R * 715;
        float tail = obih[R] + obhh[R];
#pragma unroll
        for (int r = 0; r < 10; r++) tail += w[641 + r] * fcb_l[r];
#pragma unroll 8
        for (int k = 0; k < 64; k++) tail += w[651 + k] * pz_l[k];
        float acc[16];
#pragma unroll
        for (int m = 0; m < 16; m++) acc[m] = tail;
        for (int t = j; t < 16 * 256; t += 512) xs[t >> 8][t & 255] = ne[i0 * 256 + t];
        __syncthreads();
#pragma unroll 4
        for (int k = 0; k < 256; k++) {
            float wv = w[k];
#pragma unroll
            for (int m = 0; m < 16; m++) acc[m] += wv * xs[m][k];
        }
        __syncthreads();
        for (int t = j; t < 16 * 256; t += 512) {
            int m = t >> 8, k = t & 255;
            xs[m][k] = be[(bn[i0 + m] - bn0) * 256 + k];
        }
        __syncthreads();
#pragma unroll 4
        for (int k = 0; k < 256; k++) {
            float wv = w[256 + k];
#pragma unroll
            for (int m = 0; m < 16; m++) acc[m] += wv * xs[m][k];
        }
        __syncthreads();
        for (int t = j; t < 16 * 128; t += 512) {
            int m = t >> 7, k = t & 127;
            xm[m][k] = me[(mn[i0 + m] - mn0) * 128 + k];
        }
        __syncthreads();
#pragma unroll 4
        for (int k = 0; k < 128; k++) {
            float wv = w[512 + k];
#pragma unroll
            for (int m = 0; m < 16; m++) acc[m] += wv * xm[m][k];
        }
#pragma unroll
        for (int m = 0; m < 16; m++) opre[(i0 + m) * 512 + j] = acc[m];
    } else {
        // ================= tpre role =================
        const int i0 = (blockIdx.x - NB) * 16;
        {
            bool need = false;
#pragma unroll
            for (int m = 0; m < 16; m++) {
                int idx = i0 + m;
                need = need || (idx == 0) || (bn[idx] > bn[idx - 1]);
            }
            if (!need) return;
        }
        __syncthreads();
        const float* w = tWih + R * 467;
        float tail = tbih[R] + tbhh[R];
#pragma unroll 8
        for (int k = 0; k < 64; k++) tail += w[403 + k] * pz_l[k];
        float acc[16];
#pragma unroll
        for (int m = 0; m < 16; m++) acc[m] = tail;
        for (int t = j; t < 16 * 256; t += 512) {
            int m = t >> 8, k = t & 255;
            xs[m][k] = be[(bn[i0 + m] - bn0) * 256 + k];
        }
        if (j < 128) {
            int m = j >> 3, k = j & 7;
            xr[m][k] = ri[(bn[i0 + m] - bn0) * 8 + k];
        }
        __syncthreads();
#pragma unroll 4
        for (int k = 0; k < 256; k++) {
            float wv = w[k];
#pragma unroll
            for (int m = 0; m < 16; m++) acc[m] += wv * xs[m][k];
        }
#pragma unroll
        for (int k = 0; k < 8; k++) {
            float wv = w[385 + k];
#pragma unroll
            for (int m = 0; m < 16; m++) acc[m] += wv * xr[m][k];
        }
        __syncthreads();
        for (int t = j; t < 16 * 128; t += 512) {
            int m = t >> 7, k = t & 127;
            xm[m][k] = me[(mn[i0 + m] - mn0) * 128 + k];
        }
        __syncthreads();
#pragma unroll 4
        for (int k = 0; k < 128; k++) {
            float wv = w[256 + k];
#pragma unroll
            for (int m = 0; m < 16; m++) acc[m] += wv * xm[m][k];
        }
#pragma unroll
        for (int m = 0; m < 16; m++) tpre[(i0 + m) * 512 + j] = acc[m];
    }
}

// fc+sim -> rings, optionally out[NOTE,1:11].
#define FC_SIM_RING(FHP_OFF, NOTE, OUTOK) do { \
    const int r_ = lane & 15; \
    const int cch_ = lane >> 4; \
    const uint4* fv_ = (const uint4*)(fh_pk + (FHP_OFF)) + (cch_ << 2); \
    const uint4* wv_ = (const uint4*)(fcw_pk + r_ * 68) + (cch_ << 2); \
    float a0_ = 0.f, a1_ = 0.f, a2_ = 0.f, a3_ = 0.f; \
    _Pragma("unroll") \
    for (int q_ = 0; q_ < 4; q_++) { \
        uint4 aa_ = wv_[q_]; uint4 bb_ = fv_[q_]; \
        a0_ = fdot2f(aa_.x, bb_.x, a0_); \
        a1_ = fdot2f(aa_.y, bb_.y, a1_); \
        a2_ = fdot2f(aa_.z, bb_.z, a2_); \
        a3_ = fdot2f(aa_.w, bb_.w, a3_); \
    } \
    float acc_ = (a0_ + a1_) + (a2_ + a3_); \
    acc_ += __shfl_xor(acc_, 16); \
    acc_ += __shfl_xor(acc_, 32); \
    float ofc_ = acc_ + fcb_lds[r_]; \
    float a_ = attnb_lds[r_]; \
    _Pragma("unroll") \
    for (int c_ = 0; c_ < 10; c_++) a_ += attnW_lds[r_ * 10 + c_] * rdl(ofc_, c_); \
    float simv_ = tanhc(a_) * attncv_lds[r_]; \
    simv_ += qp<0xB1>(simv_); \
    simv_ += qp<0x4E>(simv_); \
    simv_ += qp<0x141>(simv_); \
    simv_ += qp<0x140>(simv_); \
    if (lane < 10) { \
        out_ring[((NOTE) & 255) * 10 + lane] = ofc_; \
        if (OUTOK) out[(NOTE) * 11 + 1 + lane] = ofc_; \
    } \
    if (lane == 0) sim_ring[(NOTE) & 255] = simv_; \
} while (0)

// ---------------- chunked scan: N_CHUNKS blocks, self-computed bounds, direct out writes ----------------
__global__
__attribute__((amdgpu_flat_work_group_size(512, 512), amdgpu_waves_per_eu(2, 2)))
void seq_kernel(
    const float* __restrict__ oWih, const float* __restrict__ oWhh,
    const float* __restrict__ tWih, const float* __restrict__ tWhh,
    const float* __restrict__ fcW, const float* __restrict__ fcb,
    const float* __restrict__ tfcW, const float* __restrict__ tfcb,
    const float* __restrict__ attnW, const float* __restrict__ attnb,
    const float* __restrict__ attncv,
    const int* __restrict__ bn_g,
    const float* __restrict__ opre, const float* __restrict__ tpre,
    float* __restrict__ out) {
    const int j = threadIdx.x;
    const int lane = j & 63;
    const int wv_id = j >> 6;
    const int blk = blockIdx.x;

    __shared__ __align__(16) uint_t t2_lds[512 * 64];
    __shared__ __align__(16) uint_t fh_pk[2 * 64];
    __shared__ __align__(16) uint_t th_pk[2 * 64];
    __shared__ __align__(16) uint_t fcw_pk[16 * 68];
    __shared__ float attnW_lds[160];
    __shared__ float attnb_lds[16], attncv_lds[16], fcb_lds[16];
    __shared__ uint_t rn_pk[5];
    __shared__ float rn_tmp[10];
    __shared__ __align__(16) float tpart8[8];
    __shared__ float out_ring[256 * 10];
    __shared__ float sim_ring[256];
    __shared__ unsigned char bnd_lds[2048];

    for (int idx = j; idx < 16 * 68; idx += 512) {
        int r = idx / 68, k = idx - r * 68;
        uint_t v = 0;
        if (r < 10 && k < 64) v = pk2(fcW[r * 128 + 2 * k], fcW[r * 128 + 2 * k + 1]);
        fcw_pk[idx] = v;
    }
    for (int idx = j; idx < N_NOTES; idx += 512)
        bnd_lds[idx] = (idx == 0) ? 1 : (bn_g[idx] > bn_g[idx - 1]);
    if (j < 160) attnW_lds[j] = (j < 100) ? attnW[j] : 0.f;
    if (j < 16) {
        attnb_lds[j] = (j < 10) ? attnb[j] : 0.f;
        attncv_lds[j] = (j < 10) ? attncv[j] : 0.f;
        fcb_lds[j] = (j < 10) ? fcb[j] : 0.f;
    }
    if (j < 5) rn_pk[j] = 0;
    if (j < 128) { fh_pk[j] = 0; th_pk[j] = 0; }
    if (j < 8) tpart8[j] = 0.f;
    __syncthreads();

    // ---- chunk bounds (all threads compute identically from bnd_lds) ----
    int s = (blk * N_NOTES) / N_CHUNKS;
    while (s > 0 && !bnd_lds[s]) s--;
    const int ostart = s;
    int w = ostart - WARMUP;
    if (w < 0) w = 0;
    while (w > 0 && !bnd_lds[w]) w--;
    const int wstart = w;
    int e = N_NOTES;
    if (blk + 1 < N_CHUNKS) {
        e = ((blk + 1) * N_NOTES) / N_CHUNKS;
        while (e > 0 && !bnd_lds[e]) e--;
    }
    const int iend = e;

    const int R = ((j & 3) << 7) + (j >> 2);
    const int u = j >> 2;
    const int g = j & 3;
    float c1[10];
#pragma unroll
    for (int r = 0; r < 10; r++) c1[r] = oWih[R * 715 + 641 + r];
    float d0 = 0.f;
#pragma unroll
    for (int r = 0; r < 10; r++) d0 += c1[r] * fcb_lds[r];
    const float ocol = oWih[R * 715 + 640];
    const float twc384 = tWih[R * 467 + 384];
    uvec32 w2a, w2b;
    {
        const float* owr = oWhh + R * 128;
#pragma unroll
        for (int q = 0; q < 32; q++) {
            float a = owr[2 * q], b = owr[2 * q + 1];
#pragma unroll
            for (int r = 0; r < 10; r++) {
                a += c1[r] * fcW[r * 128 + 2 * q];
                b += c1[r] * fcW[r * 128 + 2 * q + 1];
            }
            w2a[q] = pk2(a, b);
        }
#pragma unroll
        for (int q = 0; q < 32; q++) {
            float a = owr[64 + 2 * q], b = owr[64 + 2 * q + 1];
#pragma unroll
            for (int r = 0; r < 10; r++) {
                a += c1[r] * fcW[r * 128 + 64 + 2 * q];
                b += c1[r] * fcW[r * 128 + 64 + 2 * q + 1];
            }
            w2b[q] = pk2(a, b);
        }
    }
    {
        const float* twr = tWhh + R * 128;
#pragma unroll
        for (int q = 0; q < 64; q++) {
            uint_t v = pk2(twr[2 * q] + twc384 * tfcW[2 * q],
                           twr[2 * q + 1] + twc384 * tfcW[2 * q + 1]);
            t2_lds[j * 64 + (((q >> 2) ^ (j & 15)) << 2) + (q & 3)] = v;
        }
    }
    uint_t twcp[5];
#pragma unroll
    for (int r = 0; r < 5; r++)
        twcp[r] = pk2(tWih[R * 467 + 393 + 2 * r], tWih[R * 467 + 393 + 2 * r + 1]);
    const float const_t = twc384 * tfcb[0];
    const float tfcw_u = tfcW[u];
    const float tfcb_s = tfcb[0];

    float c_st = 0.f, tc_st = 0.f;
    float tempo_reg = 0.f;
    int prev_end = wstart;
    int bp = 0;
    bool bnd_prev = false;
    bool bnd_cur = true;   // wstart is a boundary by construction
    float pre_o = opre[wstart * 512 + j];
    float pre_t = tpre[wstart * 512 + j];
    __syncthreads();

#pragma unroll 1
    for (int i = wstart; i < iend; ++i) {
        if (bnd_prev) {
            float4 p0 = *(const float4*)&tpart8[0];
            float4 p1 = *(const float4*)&tpart8[4];
            tempo_reg = ((p0.x + p0.y) + (p0.z + p0.w)) + ((p1.x + p1.y) + (p1.z + p1.w)) + tfcb_s;
        }
        if (j == 0 && i > wstart && (i - 1) >= ostart) out[(i - 1) * 11] = tempo_reg;
        const int par = i & 1;
        const int ip1 = (i + 1 < iend) ? (i + 1) : (iend - 1);
        // global boundary flag: also fires at i == iend-1 (iend is next chunk's ostart)
        const bool bnd_nxt = (i + 1 < N_NOTES) && bnd_lds[i + 1];
        const float pre_o_nxt = opre[ip1 * 512 + j];
        const float pre_t_nxt = tpre[ip1 * 512 + j];
        {
            float zb = pre_o + ocol * tempo_reg;
            if (i == 0) zb -= d0;
            const uint4* fp = (const uint4*)(fh_pk + ((par ^ 1) << 6));
            float a0 = zb, a1 = 0.f, a2 = 0.f, a3 = 0.f;
#pragma unroll
            for (int q = 0; q < 8; q++) {
                uint4 v = fp[q];
                a0 = fdot2f(w2a[4 * q + 0], v.x, a0);
                a1 = fdot2f(w2a[4 * q + 1], v.y, a1);
                a2 = fdot2f(w2a[4 * q + 2], v.z, a2);
                a3 = fdot2f(w2a[4 * q + 3], v.w, a3);
            }
#pragma unroll
            for (int q = 0; q < 8; q++) {
                uint4 v = fp[8 + q];
                a0 = fdot2f(w2b[4 * q + 0], v.x, a0);
                a1 = fdot2f(w2b[4 * q + 1], v.y, a1);
                a2 = fdot2f(w2b[4 * q + 2], v.z, a2);
                a3 = fdot2f(w2b[4 * q + 3], v.w, a3);
            }
            float z = (a0 + a1) + (a2 + a3);
            float x1 = qp<0xB1>(z);
            float x2 = qp<0x4E>(z);
            float x3 = qp<0x1B>(z);
            float zi = (g == 1) ? x1 : (g == 2) ? x2 : (g == 3) ? x3 : z;
            float zf = (g == 0) ? x1 : (g == 1) ? z  : (g == 2) ? x3 : x2;
            float zg = (g == 0) ? x2 : (g == 1) ? x3 : (g == 2) ? z  : x1;
            float zo = (g == 0) ? x3 : (g == 1) ? x2 : (g == 2) ? x1 : z;
            c_st = sigm(zf) * c_st + sigm(zi) * tanhc(zg);
            float h = sigm(zo) * tanhc(c_st);
            if (g == 0) ((_Float16*)fh_pk)[(par << 7) + u] = (_Float16)h;
        }
        if (bnd_cur) {
            float ztb = (i == 0) ? 0.f : const_t;
#pragma unroll
            for (int r = 0; r < 5; r++) ztb = fdot2f(twcp[r], rn_pk[r], ztb);
            const uint4* t2v = (const uint4*)t2_lds + (j << 4);
            const uint4* thv = (const uint4*)(th_pk + ((bp ^ 1) << 6));
            float b0 = pre_t + ztb, b1 = 0.f, b2 = 0.f, b3 = 0.f;
#pragma unroll
            for (int s2 = 0; s2 < 16; s2++) {
                uint4 w2 = t2v[s2 ^ (j & 15)];
                uint4 v = thv[s2];
                b0 = fdot2f(w2.x, v.x, b0);
                b1 = fdot2f(w2.y, v.y, b1);
                b2 = fdot2f(w2.z, v.z, b2);
                b3 = fdot2f(w2.w, v.w, b3);
            }
            float zt = (b0 + b1) + (b2 + b3);
            float y1 = qp<0xB1>(zt);
            float y2 = qp<0x4E>(zt);
            float y3 = qp<0x1B>(zt);
            float ti = (g == 1) ? y1 : (g == 2) ? y2 : (g == 3) ? y3 : zt;
            float tf = (g == 0) ? y1 : (g == 1) ? zt : (g == 2) ? y3 : y2;
            float tg = (g == 0) ? y2 : (g == 1) ? y3 : (g == 2) ? zt : y1;
            float to = (g == 0) ? y3 : (g == 1) ? y2 : (g == 2) ? y1 : zt;
            tc_st = sigm(tf) * tc_st + sigm(ti) * tanhc(tg);
            float th = sigm(to) * tanhc(tc_st);
            if (g == 0) ((_Float16*)th_pk)[(bp << 7) + u] = (_Float16)th;
            float qv = 0.25f * tfcw_u * th;
            qv += qp<0xB1>(qv);
            qv += qp<0x4E>(qv);
            qv += qp<0x141>(qv);
            qv += qp<0x140>(qv);
            qv += dppmov<0x142, 0xA>(qv, 0.f);
            qv += dppmov<0x143, 0xC>(qv, 0.f);
            float wsum = rdl(qv, 63);
            if (lane == 0) tpart8[wv_id] = wsum;
            prev_end = i;
        } else if (i > wstart && wv_id == (i & 7)) {
            // deferred fc/sim/out for note i-1
            FC_SIM_RING(((par ^ 1) << 6), i - 1, (i - 1) >= ostart);
        }
        BAR();
        if (bnd_nxt) {
            if (j < 64) {
                // eager fc/sim/out for note i (the pre-boundary note)
                FC_SIM_RING((par << 6), i, i >= ostart);
                LGKM0();
                const int L = i + 1 - prev_end;
                float m = -1e30f;
                for (int b = lane; b < L; b += 64) m = fmaxf(m, sim_ring[(prev_end + b) & 255]);
                WRED_MAX(m);
                float es = 0.f;
                float accv[10];
#pragma unroll
                for (int r = 0; r < 10; r++) accv[r] = 0.f;
                for (int b = lane; b < L; b += 64) {
                    int idx = (prev_end + b) & 255;
                    float e2 = __expf(sim_ring[idx] - m);
                    es += e2;
#pragma unroll
                    for (int r = 0; r < 10; r++) accv[r] += e2 * out_ring[idx * 10 + r];
                }
                WRED_ADD(es);
#pragma unroll
                for (int r = 0; r < 10; r++) WRED_ADD(accv[r]);
                float inv = 1.f / fmaxf(es, 1e-20f);
                if (lane < 10) rn_tmp[lane] = accv[lane] * inv;
                LGKM0();
                if (lane < 5) rn_pk[lane] = pk2(rn_tmp[2 * lane], rn_tmp[2 * lane + 1]);
            }
            BAR();
        }
        bnd_prev = bnd_cur;
        if (bnd_cur) bp ^= 1;
        pre_o = pre_o_nxt;
        pre_t = pre_t_nxt;
        bnd_cur = bnd_nxt;
    }
    // final tempo of this chunk's range
    if (bnd_prev) {
        float4 p0 = *(const float4*)&tpart8[0];
        float4 p1 = *(const float4*)&tpart8[4];
        tempo_reg = ((p0.x + p0.y) + (p0.z + p0.w)) + ((p1.x + p1.y) + (p1.z + p1.w)) + tfcb_s;
    }
    if (j == 0 && iend > wstart && (iend - 1) >= ostart) out[(iend - 1) * 11] = tempo_reg;
    // epilogue fc for the global last note (no eager covers it; last chunk only)
    if (iend == N_NOTES && iend > wstart && j < 64) {
        FC_SIM_RING((((N_NOTES - 1) & 1) << 6), N_NOTES - 1, true);
    }
}

extern "C" void kernel_launch(void* const* d_in, const int* in_sizes, int n_in,
                              void* d_out, int out_size, void* d_ws, size_t ws_size,
                              hipStream_t stream) {
    (void)in_sizes; (void)n_in; (void)out_size; (void)ws_size;
    const float* ne     = (const float*)d_in[0];
    const float* be     = (const float*)d_in[1];
    const float* me     = (const float*)d_in[2];
    const float* ri     = (const float*)d_in[3];
    const float* perf   = (const float*)d_in[4];
    const int*   bn     = (const int*)d_in[5];
    const int*   mn     = (const int*)d_in[6];
    const float* expW   = (const float*)d_in[7];
    const float* expb   = (const float*)d_in[8];
    const float* tWih   = (const float*)d_in[9];
    const float* tWhh   = (const float*)d_in[10];
    const float* tbih   = (const float*)d_in[11];
    const float* tbhh   = (const float*)d_in[12];
    const float* tfcW   = (const float*)d_in[13];
    const float* tfcb   = (const float*)d_in[14];
    const float* attnW  = (const float*)d_in[15];
    const float* attnb  = (const float*)d_in[16];
    const float* attncv = (const float*)d_in[17];
    const float* oWih   = (const float*)d_in[18];
    const float* oWhh   = (const float*)d_in[19];
    const float* obih   = (const float*)d_in[20];
    const float* obhh   = (const float*)d_in[21];
    const float* fcW    = (const float*)d_in[22];
    const float* fcb    = (const float*)d_in[23];

    float* opre = (float*)d_ws;
    float* tpre = opre + N_NOTES * 512;
    float* out  = (float*)d_out;

    pre_kernel<<<2 * NB, 512, 0, stream>>>(oWih, obih, obhh, tWih, tbih, tbhh,
                                           ne, be, me, ri, expW, expb, perf, fcb,
                                           bn, mn, opre, tpre);
    seq_kernel<<<N_CHUNKS, 512, 0, stream>>>(oWih, oWhh, tWih, tWhh, fcW, fcb, tfcW, tfcb,
                                             attnW, attnb, attncv, bn, opre, tpre, out);
}

// Round 21
// 266.823 us; speedup vs baseline: 1.5512x; 1.0589x over previous
//
#include <hip/hip_runtime.h>
#include <hip/hip_bf16.h>

typedef unsigned short ushort_t;
typedef unsigned int uint_t;
typedef _Float16 h2v __attribute__((ext_vector_type(2)));
typedef uint_t uvec32 __attribute__((ext_vector_type(32)));

#define N_NOTES 2000
#define N_CHUNKS 256
#define WARMUP 64
#define NB 125   // N_NOTES/16

__device__ __forceinline__ float sigm(float x) { return 1.0f / (1.0f + __expf(-x)); }
__device__ __forceinline__ float tanhc(float x) {
    x = fminf(fmaxf(x, -15.f), 15.f);
    float e = __expf(2.f * x);
    return (e - 1.f) / (e + 1.f);
}
__device__ __forceinline__ uint_t pk2(float a, float b) {
    h2v h; h[0] = (_Float16)a; h[1] = (_Float16)b;
    return __builtin_bit_cast(uint_t, h);
}

#if __has_builtin(__builtin_amdgcn_fdot2)
__device__ __forceinline__ float fdot2f(uint_t a, uint_t b, float c) {
    return __builtin_amdgcn_fdot2(__builtin_bit_cast(h2v, a), __builtin_bit_cast(h2v, b), c, false);
}
#else
__device__ __forceinline__ float fdot2f(uint_t a, uint_t b, float c) {
    h2v x = __builtin_bit_cast(h2v, a), y = __builtin_bit_cast(h2v, b);
    return c + (float)x[0] * (float)y[0] + (float)x[1] * (float)y[1];
}
#endif

// ---- DPP cross-lane (VALU pipe) ----
template <int CTRL, int RMASK = 0xF>
__device__ __forceinline__ float dppmov(float src, float old) {
    int r = __builtin_amdgcn_update_dpp(__builtin_bit_cast(int, old),
                                        __builtin_bit_cast(int, src),
                                        CTRL, RMASK, 0xF, false);
    return __builtin_bit_cast(float, r);
}
template <int CTRL>
__device__ __forceinline__ float qp(float v) { return dppmov<CTRL>(v, v); }
__device__ __forceinline__ float rdl(float v, int l) {
    return __builtin_bit_cast(float, __builtin_amdgcn_readlane(__builtin_bit_cast(int, v), l));
}
#define WRED_ADD(x) do { x += qp<0xB1>(x); x += qp<0x4E>(x); x += qp<0x141>(x); x += qp<0x140>(x); \
                         x += __shfl_xor(x, 16); x += __shfl_xor(x, 32); } while (0)
#define WRED_MAX(x) do { x = fmaxf(x, qp<0xB1>(x)); x = fmaxf(x, qp<0x4E>(x)); \
                         x = fmaxf(x, qp<0x141>(x)); x = fmaxf(x, qp<0x140>(x)); \
                         x = fmaxf(x, __shfl_xor(x, 16)); x = fmaxf(x, __shfl_xor(x, 32)); } while (0)

#define BAR() do { \
    asm volatile("s_waitcnt lgkmcnt(0)" ::: "memory"); \
    __builtin_amdgcn_s_barrier(); \
    asm volatile("" ::: "memory"); \
} while (0)
#define LGKM0() asm volatile("s_waitcnt lgkmcnt(0)" ::: "memory")

// ---------------- pre: concatenated grids — blocks 0..124 opre, 125..249 tpre ----------------
__global__ __launch_bounds__(512, 2) void pre_kernel(
    const float* __restrict__ oWih, const float* __restrict__ obih, const float* __restrict__ obhh,
    const float* __restrict__ tWih, const float* __restrict__ tbih, const float* __restrict__ tbhh,
    const float* __restrict__ ne, const float* __restrict__ be, const float* __restrict__ me,
    const float* __restrict__ ri, const float* __restrict__ expW, const float* __restrict__ expb,
    const float* __restrict__ perf, const float* __restrict__ fcb,
    const int* __restrict__ bn, const int* __restrict__ mn,
    float* __restrict__ opre, float* __restrict__ tpre) {
    const int j = threadIdx.x;
    const int R = ((j & 3) << 7) + (j >> 2);   // gate-major row
    __shared__ float xs[16][256];
    __shared__ float xm[16][128];
    __shared__ float xr[16][8];
    __shared__ float pz_l[64];
    __shared__ float fcb_l[10];
    if (j < 64) {
        float acc = expb[j];
#pragma unroll
        for (int k = 0; k < 16; k++) acc += expW[j * 16 + k] * perf[k];
        pz_l[j] = fmaxf(acc, 0.f);
    }
    if (j < 10) fcb_l[j] = fcb[j];
    const int bn0 = bn[0], mn0 = mn[0];

    if (blockIdx.x < NB) {
        // ================= opre role =================
        const int i0 = blockIdx.x * 16;
        __syncthreads();
        const float* w = oWih + R * 715;
        float tail = obih[R] + obhh[R];
#pragma unroll
        for (int r = 0; r < 10; r++) tail += w[641 + r] * fcb_l[r];
#pragma unroll 8
        for (int k = 0; k < 64; k++) tail += w[651 + k] * pz_l[k];
        float acc[16];
#pragma unroll
        for (int m = 0; m < 16; m++) acc[m] = tail;
        for (int t = j; t < 16 * 256; t += 512) xs[t >> 8][t & 255] = ne[i0 * 256 + t];
        __syncthreads();
#pragma unroll 4
        for (int k = 0; k < 256; k++) {
            float wv = w[k];
#pragma unroll
            for (int m = 0; m < 16; m++) acc[m] += wv * xs[m][k];
        }
        __syncthreads();
        for (int t = j; t < 16 * 256; t += 512) {
            int m = t >> 8, k = t & 255;
            xs[m][k] = be[(bn[i0 + m] - bn0) * 256 + k];
        }
        __syncthreads();
#pragma unroll 4
        for (int k = 0; k < 256; k++) {
            float wv = w[256 + k];
#pragma unroll
            for (int m = 0; m < 16; m++) acc[m] += wv * xs[m][k];
        }
        __syncthreads();
        for (int t = j; t < 16 * 128; t += 512) {
            int m = t >> 7, k = t & 127;
            xm[m][k] = me[(mn[i0 + m] - mn0) * 128 + k];
        }
        __syncthreads();
#pragma unroll 4
        for (int k = 0; k < 128; k++) {
            float wv = w[512 + k];
#pragma unroll
            for (int m = 0; m < 16; m++) acc[m] += wv * xm[m][k];
        }
#pragma unroll
        for (int m = 0; m < 16; m++) opre[(i0 + m) * 512 + j] = acc[m];
    } else {
        // ================= tpre role =================
        const int i0 = (blockIdx.x - NB) * 16;
        {
            bool need = false;
#pragma unroll
            for (int m = 0; m < 16; m++) {
                int idx = i0 + m;
                need = need || (idx == 0) || (bn[idx] > bn[idx - 1]);
            }
            if (!need) return;
        }
        __syncthreads();
        const float* w = tWih + R * 467;
        float tail = tbih[R] + tbhh[R];
#pragma unroll 8
        for (int k = 0; k < 64; k++) tail += w[403 + k] * pz_l[k];
        float acc[16];
#pragma unroll
        for (int m = 0; m < 16; m++) acc[m] = tail;
        for (int t = j; t < 16 * 256; t += 512) {
            int m = t >> 8, k = t & 255;
            xs[m][k] = be[(bn[i0 + m] - bn0) * 256 + k];
        }
        if (j < 128) {
            int m = j >> 3, k = j & 7;
            xr[m][k] = ri[(bn[i0 + m] - bn0) * 8 + k];
        }
        __syncthreads();
#pragma unroll 4
        for (int k = 0; k < 256; k++) {
            float wv = w[k];
#pragma unroll
            for (int m = 0; m < 16; m++) acc[m] += wv * xs[m][k];
        }
#pragma unroll
        for (int k = 0; k < 8; k++) {
            float wv = w[385 + k];
#pragma unroll
            for (int m = 0; m < 16; m++) acc[m] += wv * xr[m][k];
        }
        __syncthreads();
        for (int t = j; t < 16 * 128; t += 512) {
            int m = t >> 7, k = t & 127;
            xm[m][k] = me[(mn[i0 + m] - mn0) * 128 + k];
        }
        __syncthreads();
#pragma unroll 4
        for (int k = 0; k < 128; k++) {
            float wv = w[256 + k];
#pragma unroll
            for (int m = 0; m < 16; m++) acc[m] += wv * xm[m][k];
        }
#pragma unroll
        for (int m = 0; m < 16; m++) tpre[(i0 + m) * 512 + j] = acc[m];
    }
}

// fc+sim -> rings, optionally out[NOTE,1:11].
#define FC_SIM_RING(FHP_OFF, NOTE, OUTOK) do { \
    const int r_ = lane & 15; \
    const int cch_ = lane >> 4; \
    const uint4* fv_ = (const uint4*)(fh_pk + (FHP_OFF)) + (cch_ << 2); \
    const uint4* wv_ = (const uint4*)(fcw_pk + r_ * 68) + (cch_ << 2); \
    float a0_ = 0.f, a1_ = 0.f, a2_ = 0.f, a3_ = 0.f; \
    _Pragma("unroll") \
    for (int q_ = 0; q_ < 4; q_++) { \
        uint4 aa_ = wv_[q_]; uint4 bb_ = fv_[q_]; \
        a0_ = fdot2f(aa_.x, bb_.x, a0_); \
        a1_ = fdot2f(aa_.y, bb_.y, a1_); \
        a2_ = fdot2f(aa_.z, bb_.z, a2_); \
        a3_ = fdot2f(aa_.w, bb_.w, a3_); \
    } \
    float acc_ = (a0_ + a1_) + (a2_ + a3_); \
    acc_ += __shfl_xor(acc_, 16); \
    acc_ += __shfl_xor(acc_, 32); \
    float ofc_ = acc_ + fcb_lds[r_]; \
    float a_ = attnb_lds[r_]; \
    _Pragma("unroll") \
    for (int c_ = 0; c_ < 10; c_++) a_ += attnW_lds[r_ * 10 + c_] * rdl(ofc_, c_); \
    float simv_ = tanhc(a_) * attncv_lds[r_]; \
    simv_ += qp<0xB1>(simv_); \
    simv_ += qp<0x4E>(simv_); \
    simv_ += qp<0x141>(simv_); \
    simv_ += qp<0x140>(simv_); \
    if (lane < 10) { \
        out_ring[((NOTE) & 255) * 10 + lane] = ofc_; \
        if (OUTOK) out[(NOTE) * 11 + 1 + lane] = ofc_; \
    } \
    if (lane == 0) sim_ring[(NOTE) & 255] = simv_; \
} while (0)

// ---------------- chunked scan: N_CHUNKS blocks, self-computed bounds, direct out writes ----------------
__global__
__attribute__((amdgpu_flat_work_group_size(512, 512), amdgpu_waves_per_eu(2, 2)))
void seq_kernel(
    const float* __restrict__ oWih, const float* __restrict__ oWhh,
    const float* __restrict__ tWih, const float* __restrict__ tWhh,
    const float* __restrict__ fcW, const float* __restrict__ fcb,
    const float* __restrict__ tfcW, const float* __restrict__ tfcb,
    const float* __restrict__ attnW, const float* __restrict__ attnb,
    const float* __restrict__ attncv,
    const int* __restrict__ bn_g,
    const float* __restrict__ opre, const float* __restrict__ tpre,
    float* __restrict__ out) {
    const int j = threadIdx.x;
    const int lane = j & 63;
    const int wv_id = j >> 6;
    const int blk = blockIdx.x;

    __shared__ __align__(16) uint_t t2_lds[512 * 64];
    __shared__ __align__(16) uint_t fh_pk[2 * 64];
    __shared__ __align__(16) uint_t th_pk[2 * 64];
    __shared__ __align__(16) uint_t fcw_pk[16 * 68];
    __shared__ float attnW_lds[160];
    __shared__ float attnb_lds[16], attncv_lds[16], fcb_lds[16];
    __shared__ uint_t rn_pk[5];
    __shared__ float rn_tmp[10];
    __shared__ __align__(16) float tpart8[8];
    __shared__ float out_ring[256 * 10];
    __shared__ float sim_ring[256];
    __shared__ unsigned char bnd_lds[2048];

    for (int idx = j; idx < 16 * 68; idx += 512) {
        int r = idx / 68, k = idx - r * 68;
        uint_t v = 0;
        if (r < 10 && k < 64) v = pk2(fcW[r * 128 + 2 * k], fcW[r * 128 + 2 * k + 1]);
        fcw_pk[idx] = v;
    }
    for (int idx = j; idx < N_NOTES; idx += 512)
        bnd_lds[idx] = (idx == 0) ? 1 : (bn_g[idx] > bn_g[idx - 1]);
    if (j < 160) attnW_lds[j] = (j < 100) ? attnW[j] : 0.f;
    if (j < 16) {
        attnb_lds[j] = (j < 10) ? attnb[j] : 0.f;
        attncv_lds[j] = (j < 10) ? attncv[j] : 0.f;
        fcb_lds[j] = (j < 10) ? fcb[j] : 0.f;
    }
    if (j < 5) rn_pk[j] = 0;
    if (j < 128) { fh_pk[j] = 0; th_pk[j] = 0; }
    if (j < 8) tpart8[j] = 0.f;
    __syncthreads();

    // ---- chunk bounds (all threads compute identically from bnd_lds) ----
    int s = (blk * N_NOTES) / N_CHUNKS;
    while (s > 0 && !bnd_lds[s]) s--;
    const int ostart = s;
    int w = ostart - WARMUP;
    if (w < 0) w = 0;
    while (w > 0 && !bnd_lds[w]) w--;
    const int wstart = w;
    int e = N_NOTES;
    if (blk + 1 < N_CHUNKS) {
        e = ((blk + 1) * N_NOTES) / N_CHUNKS;
        while (e > 0 && !bnd_lds[e]) e--;
    }
    const int iend = e;

    const int R = ((j & 3) << 7) + (j >> 2);
    const int u = j >> 2;
    const int g = j & 3;
    float c1[10];
#pragma unroll
    for (int r = 0; r < 10; r++) c1[r] = oWih[R * 715 + 641 + r];
    float d0 = 0.f;
#pragma unroll
    for (int r = 0; r < 10; r++) d0 += c1[r] * fcb_lds[r];
    const float ocol = oWih[R * 715 + 640];
    const float twc384 = tWih[R * 467 + 384];
    uvec32 w2a, w2b;
    {
        const float* owr = oWhh + R * 128;
#pragma unroll
        for (int q = 0; q < 32; q++) {
            float a = owr[2 * q], b = owr[2 * q + 1];
#pragma unroll
            for (int r = 0; r < 10; r++) {
                a += c1[r] * fcW[r * 128 + 2 * q];
                b += c1[r] * fcW[r * 128 + 2 * q + 1];
            }
            w2a[q] = pk2(a, b);
        }
#pragma unroll
        for (int q = 0; q < 32; q++) {
            float a = owr[64 + 2 * q], b = owr[64 + 2 * q + 1];
#pragma unroll
            for (int r = 0; r < 10; r++) {
                a += c1[r] * fcW[r * 128 + 64 + 2 * q];
                b += c1[r] * fcW[r * 128 + 64 + 2 * q + 1];
            }
            w2b[q] = pk2(a, b);
        }
    }
    {
        const float* twr = tWhh + R * 128;
#pragma unroll
        for (int q = 0; q < 64; q++) {
            uint_t v = pk2(twr[2 * q] + twc384 * tfcW[2 * q],
                           twr[2 * q + 1] + twc384 * tfcW[2 * q + 1]);
            t2_lds[j * 64 + (((q >> 2) ^ (j & 15)) << 2) + (q & 3)] = v;
        }
    }
    uint_t twcp[5];
#pragma unroll
    for (int r = 0; r < 5; r++)
        twcp[r] = pk2(tWih[R * 467 + 393 + 2 * r], tWih[R * 467 + 393 + 2 * r + 1]);
    const float const_t = twc384 * tfcb[0];
    const float tfcw_u = tfcW[u];
    const float tfcb_s = tfcb[0];

    float c_st = 0.f, tc_st = 0.f;
    float tempo_reg = 0.f;
    int prev_end = wstart;
    int bp = 0;
    bool bnd_prev = false;
    bool bnd_cur = true;   // wstart is a boundary by construction
    float pre_o = opre[wstart * 512 + j];
    float pre_t = tpre[wstart * 512 + j];
    __syncthreads();

#pragma unroll 1
    for (int i = wstart; i < iend; ++i) {
        if (bnd_prev) {
            float4 p0 = *(const float4*)&tpart8[0];
            float4 p1 = *(const float4*)&tpart8[4];
            tempo_reg = ((p0.x + p0.y) + (p0.z + p0.w)) + ((p1.x + p1.y) + (p1.z + p1.w)) + tfcb_s;
        }
        if (j == 0 && i > wstart && (i - 1) >= ostart) out[(i - 1) * 11] = tempo_reg;
        const int par = i & 1;
        const int ip1 = (i + 1 < iend) ? (i + 1) : (iend - 1);
        // global boundary flag: also fires at i == iend-1 (iend is next chunk's ostart)
        const bool bnd_nxt = (i + 1 < N_NOTES) && bnd_lds[i + 1];
        const float pre_o_nxt = opre[ip1 * 512 + j];
        const float pre_t_nxt = tpre[ip1 * 512 + j];
        {
            float zb = pre_o + ocol * tempo_reg;
            if (i == 0) zb -= d0;
            const uint4* fp = (const uint4*)(fh_pk + ((par ^ 1) << 6));
            float a0 = zb, a1 = 0.f, a2 = 0.f, a3 = 0.f;
#pragma unroll
            for (int q = 0; q < 8; q++) {
                uint4 v = fp[q];
                a0 = fdot2f(w2a[4 * q + 0], v.x, a0);
                a1 = fdot2f(w2a[4 * q + 1], v.y, a1);
                a2 = fdot2f(w2a[4 * q + 2], v.z, a2);
                a3 = fdot2f(w2a[4 * q + 3], v.w, a3);
            }
#pragma unroll
            for (int q = 0; q < 8; q++) {
                uint4 v = fp[8 + q];
                a0 = fdot2f(w2b[4 * q + 0], v.x, a0);
                a1 = fdot2f(w2b[4 * q + 1], v.y, a1);
                a2 = fdot2f(w2b[4 * q + 2], v.z, a2);
                a3 = fdot2f(w2b[4 * q + 3], v.w, a3);
            }
            float z = (a0 + a1) + (a2 + a3);
            float x1 = qp<0xB1>(z);
            float x2 = qp<0x4E>(z);
            float x3 = qp<0x1B>(z);
            float zi = (g == 1) ? x1 : (g == 2) ? x2 : (g == 3) ? x3 : z;
            float zf = (g == 0) ? x1 : (g == 1) ? z  : (g == 2) ? x3 : x2;
            float zg = (g == 0) ? x2 : (g == 1) ? x3 : (g == 2) ? z  : x1;
            float zo = (g == 0) ? x3 : (g == 1) ? x2 : (g == 2) ? x1 : z;
            c_st = sigm(zf) * c_st + sigm(zi) * tanhc(zg);
            float h = sigm(zo) * tanhc(c_st);
            if (g == 0) ((_Float16*)fh_pk)[(par << 7) + u] = (_Float16)h;
        }
        if (bnd_cur) {
            float ztb = (i == 0) ? 0.f : const_t;
#pragma unroll
            for (int r = 0; r < 5; r++) ztb = fdot2f(twcp[r], rn_pk[r], ztb);
            const uint4* t2v = (const uint4*)t2_lds + (j << 4);
            const uint4* thv = (const uint4*)(th_pk + ((bp ^ 1) << 6));
            float b0 = pre_t + ztb, b1 = 0.f, b2 = 0.f, b3 = 0.f;
#pragma unroll
            for (int s2 = 0; s2 < 16; s2++) {
                uint4 w2 = t2v[s2 ^ (j & 15)];
                uint4 v = thv[s2];
                b0 = fdot2f(w2.x, v.x, b0);
                b1 = fdot2f(w2.y, v.y, b1);
                b2 = fdot2f(w2.z, v.z, b2);
                b3 = fdot2f(w2.w, v.w, b3);
            }
            float zt = (b0 + b1) + (b2 + b3);
            float y1 = qp<0xB1>(zt);
            float y2 = qp<0x4E>(zt);
            float y3 = qp<0x1B>(zt);
            float ti = (g == 1) ? y1 : (g == 2) ? y2 : (g == 3) ? y3 : zt;
            float tf = (g == 0) ? y1 : (g == 1) ? zt : (g == 2) ? y3 : y2;
            float tg = (g == 0) ? y2 : (g == 1) ? y3 : (g == 2) ? zt : y1;
            float to = (g == 0) ? y3 : (g == 1) ? y2 : (g == 2) ? y1 : zt;
            tc_st = sigm(tf) * tc_st + sigm(ti) * tanhc(tg);
            float th = sigm(to) * tanhc(tc_st);
            if (g == 0) ((_Float16*)th_pk)[(bp << 7) + u] = (_Float16)th;
            float qv = 0.25f * tfcw_u * th;
            qv += qp<0xB1>(qv);
            qv += qp<0x4E>(qv);
            qv += qp<0x141>(qv);
            qv += qp<0x140>(qv);
            qv += dppmov<0x142, 0xA>(qv, 0.f);
            qv += dppmov<0x143, 0xC>(qv, 0.f);
            float wsum = rdl(qv, 63);
            if (lane == 0) tpart8[wv_id] = wsum;
            prev_end = i;
        } else if (i > wstart && wv_id == (i & 7)) {
            // deferred fc/sim/out for note i-1
            FC_SIM_RING(((par ^ 1) << 6), i - 1, (i - 1) >= ostart);
        }
        BAR();
        if (bnd_nxt) {
            if (j < 64) {
                // eager fc/sim/out for note i (the pre-boundary note)
                FC_SIM_RING((par << 6), i, i >= ostart);
                LGKM0();
                const int L = i + 1 - prev_end;
                float m = -1e30f;
                for (int b = lane; b < L; b += 64) m = fmaxf(m, sim_ring[(prev_end + b) & 255]);
                WRED_MAX(m);
                float es = 0.f;
                float accv[10];
#pragma unroll
                for (int r = 0; r < 10; r++) accv[r] = 0.f;
                for (int b = lane; b < L; b += 64) {
                    int idx = (prev_end + b) & 255;
                    float e2 = __expf(sim_ring[idx] - m);
                    es += e2;
#pragma unroll
                    for (int r = 0; r < 10; r++) accv[r] += e2 * out_ring[idx * 10 + r];
                }
                WRED_ADD(es);
#pragma unroll
                for (int r = 0; r < 10; r++) WRED_ADD(accv[r]);
                float inv = 1.f / fmaxf(es, 1e-20f);
                if (lane < 10) rn_tmp[lane] = accv[lane] * inv;
                LGKM0();
                if (lane < 5) rn_pk[lane] = pk2(rn_tmp[2 * lane], rn_tmp[2 * lane + 1]);
            }
            BAR();
        }
        bnd_prev = bnd_cur;
        if (bnd_cur) bp ^= 1;
        pre_o = pre_o_nxt;
        pre_t = pre_t_nxt;
        bnd_cur = bnd_nxt;
    }
    // final tempo of this chunk's range
    if (bnd_prev) {
        float4 p0 = *(const float4*)&tpart8[0];
        float4 p1 = *(const float4*)&tpart8[4];
        tempo_reg = ((p0.x + p0.y) + (p0.z + p0.w)) + ((p1.x + p1.y) + (p1.z + p1.w)) + tfcb_s;
    }
    if (j == 0 && iend > wstart && (iend - 1) >= ostart) out[(iend - 1) * 11] = tempo_reg;
    // epilogue fc for the global last note (no eager covers it; last chunk only)
    if (iend == N_NOTES && iend > wstart && j < 64) {
        FC_SIM_RING((((N_NOTES - 1) & 1) << 6), N_NOTES - 1, true);
    }
}

extern "C" void kernel_launch(void* const* d_in, const int* in_sizes, int n_in,
                              void* d_out, int out_size, void* d_ws, size_t ws_size,
                              hipStream_t stream) {
    (void)in_sizes; (void)n_in; (void)out_size; (void)ws_size;
    const float* ne     = (const float*)d_in[0];
    const float* be     = (const float*)d_in[1];
    const float* me     = (const float*)d_in[2];
    const float* ri     = (const float*)d_in[3];
    const float* perf   = (const float*)d_in[4];
    const int*   bn     = (const int*)d_in[5];
    const int*   mn     = (const int*)d_in[6];
    const float* expW   = (const float*)d_in[7];
    const float* expb   = (const float*)d_in[8];
    const float* tWih   = (const float*)d_in[9];
    const float* tWhh   = (const float*)d_in[10];
    const float* tbih   = (const float*)d_in[11];
    const float* tbhh   = (const float*)d_in[12];
    const float* tfcW   = (const float*)d_in[13];
    const float* tfcb   = (const float*)d_in[14];
    const float* attnW  = (const float*)d_in[15];
    const float* attnb  = (const float*)d_in[16];
    const float* attncv = (const float*)d_in[17];
    const float* oWih   = (const float*)d_in[18];
    const float* oWhh   = (const float*)d_in[19];
    const float* obih   = (const float*)d_in[20];
    const float* obhh   = (const float*)d_in[21];
    const float* fcW    = (const float*)d_in[22];
    const float* fcb    = (const float*)d_in[23];

    float* opre = (float*)d_ws;
    float* tpre = opre + N_NOTES * 512;
    float* out  = (float*)d_out;

    pre_kernel<<<2 * NB, 512, 0, stream>>>(oWih, obih, obhh, tWih, tbih, tbhh,
                                           ne, be, me, ri, expW, expb, perf, fcb,
                                           bn, mn, opre, tpre);
    seq_kernel<<<N_CHUNKS, 512, 0, stream>>>(oWih, oWhh, tWih, tWhh, fcW, fcb, tfcW, tfcb,
                                             attnW, attnb, attncv, bn, opre, tpre, out);
}